// Round 6
// baseline (1043.409 us; speedup 1.0000x reference)
//
#include <hip/hip_runtime.h>
#include <math.h>

#define BB 8
#define NN 2048
#define HID 768
#define NHEADS 4
#define ALPHA 0.2f
#define NEGV -9e15f
#define MTOT (BB * NN)  // 16384

using short4v = __attribute__((ext_vector_type(4))) short;
using short8v = __attribute__((ext_vector_type(8))) short;
using f32x4 = __attribute__((ext_vector_type(4))) float;

__device__ __forceinline__ short f2bf(float f) {
  union { float f; unsigned u; } x;
  x.f = f;
  unsigned r = x.u + 0x7fffu + ((x.u >> 16) & 1u);
  return (short)(r >> 16);
}

__device__ __forceinline__ void cp16(const void* g, void* l) {
  __builtin_amdgcn_global_load_lds(
      (const __attribute__((address_space(1))) unsigned int*)g,
      (__attribute__((address_space(3))) unsigned int*)l, 16, 0, 0);
}

// ---------------------------------------------------------------------------
__global__ __launch_bounds__(256) void embed_kernel(
    const int* __restrict__ nf, const float* __restrict__ table,
    short* __restrict__ x) {
  long idx = (long)blockIdx.x * 256 + threadIdx.x;
  int col = (int)(idx % HID);
  long node = idx / HID;
  x[idx] = f2bf(table[(long)nf[node] * HID + col]);
}

__global__ __launch_bounds__(256) void pack_adj_kernel(
    const int* __restrict__ adj, unsigned long long* __restrict__ packed) {
  long idx = (long)blockIdx.x * 256 + threadIdx.x;
  unsigned long long m = __ballot(adj[idx] > 0);
  if ((threadIdx.x & 63) == 0) packed[idx >> 6] = m;
}

__global__ __launch_bounds__(256) void transpose_bf16(
    const float* __restrict__ W, short* __restrict__ Wt, int K, int N,
    long sIn, long sOut) {
  __shared__ float t[32][33];
  W += (long)blockIdx.z * sIn;
  Wt += (long)blockIdx.z * sOut;
  int k0 = blockIdx.x * 32, n0 = blockIdx.y * 32;
  int tx = threadIdx.x & 31, ty = threadIdx.x >> 5;
#pragma unroll
  for (int i = 0; i < 32; i += 8) t[ty + i][tx] = W[(long)(k0 + ty + i) * N + n0 + tx];
  __syncthreads();
#pragma unroll
  for (int i = 0; i < 32; i += 8)
    Wt[(long)(n0 + ty + i) * K + k0 + tx] = f2bf(t[tx][ty + i]);
}

__global__ __launch_bounds__(256) void zero_kernel(float* __restrict__ p, int n) {
  int i = blockIdx.x * 256 + threadIdx.x;
  if (i < n) p[i] = 0.f;
}

// ---------------------------------------------------------------------------
// bf16 MFMA GEMM, 128xTN tile (TN=128 or 64), BK=32, XCD swizzle,
// marching-pointer staging, LDS-repacked epilogues.
// TN=128: 4 waves of 64x64 (4x4 frags). TN=64: 4 waves of 32x64 (2x4 frags).
// mode 0: Ct bf16 [head][bb][colh][row] via LDS + fused a-dot atomics
// mode 1: Cb bf16 ELU via LDS (TN=128 only); z = hh*8+b -> col shift hh*HID
// mode 3: fused ELU + mean-pool: atomicAdd Cf[z*HID + col]
// ---------------------------------------------------------------------------
template <int TN>
__global__ __launch_bounds__(256) void mfma_gemm(
    const short* __restrict__ A, const short* __restrict__ B,
    int K, int lda, int ldb, long sA, long sB,
    float* __restrict__ Cf,
    short* __restrict__ Cb, int ldcb, long sCb,
    short* __restrict__ Ct,
    const float* __restrict__ a_vec, float* __restrict__ Wh1g,
    float* __restrict__ Wh2g, int mode) {
  __shared__ short smem[8704];  // staging (A:4096 + B:TN*32) reused as ctile
  short* As = smem;
  short* Bs = smem + 4096;
  constexpr int MI = (TN == 128) ? 4 : 2;  // m-frags per wave

  const int gx = gridDim.x, gy = gridDim.y;
  int lin = blockIdx.x + gx * (blockIdx.y + gy * blockIdx.z);
  const int per = (gx * gy * gridDim.z) >> 3;
  int work = (lin & 7) * per + (lin >> 3);
  const int bx = work % gx;
  int tmp = work / gx;
  const int by = tmp % gy;
  const int z = tmp / gy;

  A += (long)z * sA;
  B += (long)z * sB;

  const int tid = threadIdx.x;
  const int m0 = by * 128;
  const int n0 = bx * TN;

  const int lane = tid & 63;
  const int wid = tid >> 6;
  const int wm = (TN == 128) ? (wid & 1) * 64 : wid * 32;
  const int wn = (TN == 128) ? (wid >> 1) * 64 : 0;
  const int l15 = lane & 15;
  const int quad = lane >> 4;
  const int cp = quad ^ ((l15 >> 1) & 3);

  // marching-pointer staging setup (fixed LDS dests, global ptrs += 32/iter)
  const short *ga0, *ga1, *gb0, *gb1 = B;
  short *la0, *la1, *lb0, *lb1 = Bs;
  {
    int r = tid >> 2, p = tid & 3;
    int kc = p ^ ((r >> 1) & 3);
    ga0 = A + (long)(m0 + r) * lda + kc * 8;
    la0 = As + tid * 8;
    gb0 = B + (long)(n0 + r) * ldb + kc * 8;
    lb0 = Bs + tid * 8;
    int lin2 = 256 + tid;
    int r2 = lin2 >> 2, p2 = lin2 & 3;
    int kc2 = p2 ^ ((r2 >> 1) & 3);
    ga1 = A + (long)(m0 + r2) * lda + kc2 * 8;
    la1 = As + lin2 * 8;
    if constexpr (TN == 128) {
      gb1 = B + (long)(n0 + r2) * ldb + kc2 * 8;
      lb1 = Bs + lin2 * 8;
    }
  }

  f32x4 acc[MI][4];
#pragma unroll
  for (int i = 0; i < MI; ++i)
#pragma unroll
    for (int j = 0; j < 4; ++j) acc[i][j] = (f32x4){0.f, 0.f, 0.f, 0.f};

  for (int k0 = 0; k0 < K; k0 += 32) {
    cp16(ga0, la0);
    cp16(ga1, la1);
    cp16(gb0, lb0);
    if constexpr (TN == 128) cp16(gb1, lb1);
    ga0 += 32; ga1 += 32; gb0 += 32;
    if constexpr (TN == 128) gb1 += 32;
    __syncthreads();

    short8v af[MI], bfr[4];
#pragma unroll
    for (int i = 0; i < MI; ++i)
      af[i] = *(const short8v*)(As + (wm + i * 16 + l15) * 32 + cp * 8);
#pragma unroll
    for (int j = 0; j < 4; ++j)
      bfr[j] = *(const short8v*)(Bs + (wn + j * 16 + l15) * 32 + cp * 8);
#pragma unroll
    for (int i = 0; i < MI; ++i)
#pragma unroll
      for (int j = 0; j < 4; ++j)
        acc[i][j] = __builtin_amdgcn_mfma_f32_16x16x32_bf16(af[i], bfr[j],
                                                            acc[i][j], 0, 0, 0);
    __syncthreads();
  }

  // ---- epilogues (C/D layout: col=lane&15 group, row=quad*4+reg) ----
  if (mode == 1) {
    if constexpr (TN == 128) {
      // ELU -> bf16, coalesced via LDS row-major half-tiles (stride 132)
      Cb += (long)(z & 7) * sCb + (long)(z >> 3) * HID;
#pragma unroll
      for (int p = 0; p < 2; ++p) {
        if (wm == p * 64) {
#pragma unroll
          for (int i = 0; i < MI; ++i) {
            int row_l = i * 16 + quad * 4;
#pragma unroll
            for (int j = 0; j < 4; ++j) {
              int col = wn + j * 16 + l15;
#pragma unroll
              for (int reg = 0; reg < 4; ++reg) {
                float v = acc[i][j][reg];
                v = v > 0.f ? v : (__expf(v) - 1.f);
                smem[(row_l + reg) * 132 + col] = f2bf(v);
              }
            }
          }
        }
        __syncthreads();
#pragma unroll
        for (int it = 0; it < 8; ++it) {
          int idx = it * 256 + tid;
          int row_l = idx >> 5;
          int c4 = idx & 31;
          short4v ld = *(const short4v*)(smem + row_l * 132 + c4 * 4);
          *(short4v*)(Cb + (long)(m0 + p * 64 + row_l) * ldcb + n0 + c4 * 4) = ld;
        }
        __syncthreads();
      }
    }
  } else if (mode == 3) {
    // fused ELU + mean-pool: partial col sums -> atomicAdd Cf[z*HID+col]
#pragma unroll
    for (int j = 0; j < 4; ++j) {
      int col = n0 + wn + j * 16 + l15;
      float s = 0.f;
#pragma unroll
      for (int i = 0; i < MI; ++i)
#pragma unroll
        for (int reg = 0; reg < 4; ++reg) {
          float v = acc[i][j][reg];
          s += v > 0.f ? v : (__expf(v) - 1.f);
        }
      s += __shfl_xor(s, 16);
      s += __shfl_xor(s, 32);
      if (quad == 0) atomicAdd(Cf + (long)z * HID + col, s * (1.0f / NN));
    }
  } else {  // mode 0: a-dot + transposed Ct via LDS [col][row] (stride 136)
    float a1v[4], a2v[4];
    const int head0 = (n0 + wn) / HID;  // tiles never straddle head boundary
    {
#pragma unroll
      for (int j = 0; j < 4; ++j) {
        int colh = n0 + wn + j * 16 + l15 - head0 * HID;
        a1v[j] = a_vec[head0 * 2 * HID + colh];
        a2v[j] = a_vec[head0 * 2 * HID + HID + colh];
      }
    }
#pragma unroll
    for (int i = 0; i < MI; ++i) {
      int rb = m0 + wm + i * 16 + quad * 4;
#pragma unroll
      for (int reg = 0; reg < 4; ++reg) {
        float s1 = 0.f, s2 = 0.f;
#pragma unroll
        for (int j = 0; j < 4; ++j) {
          s1 = fmaf(acc[i][j][reg], a1v[j], s1);
          s2 = fmaf(acc[i][j][reg], a2v[j], s2);
        }
#pragma unroll
        for (int off = 1; off < 16; off <<= 1) {
          s1 += __shfl_xor(s1, off);
          s2 += __shfl_xor(s2, off);
        }
        if (l15 == 0) {
          long base = (long)head0 * MTOT + rb + reg;
          atomicAdd(Wh1g + base, s1);
          atomicAdd(Wh2g + base, s2);
        }
      }
    }
    const int bb = m0 >> 11;  // 128-row tile lies within one batch
    const int ml0 = m0 & 2047;
    if constexpr (TN == 128) {
#pragma unroll
      for (int p = 0; p < 2; ++p) {
        if (wn == p * 64) {
#pragma unroll
          for (int j = 0; j < 4; ++j) {
            int col_l = j * 16 + l15;
#pragma unroll
            for (int i = 0; i < MI; ++i) {
              int row_l = wm + i * 16 + quad * 4;
              short4v pk;
#pragma unroll
              for (int reg = 0; reg < 4; ++reg) pk[reg] = f2bf(acc[i][j][reg]);
              *(short4v*)(smem + col_l * 136 + row_l) = pk;
            }
          }
        }
        __syncthreads();
#pragma unroll
        for (int it = 0; it < 4; ++it) {
          int idx = it * 256 + tid;
          int col_l = idx >> 4;
          int ch = idx & 15;
          short8v ld = *(const short8v*)(smem + col_l * 136 + ch * 8);
          int col_g = n0 + p * 64 + col_l;
          int hd = col_g / HID;
          int colh = col_g - hd * HID;
          *(short8v*)(Ct + (((long)hd * BB + bb) * HID + colh) * NN + ml0 + ch * 8) = ld;
        }
        __syncthreads();
      }
    } else {  // TN == 64: one pass, waves own disjoint row ranges
      __syncthreads();
#pragma unroll
      for (int j = 0; j < 4; ++j) {
        int col_l = j * 16 + l15;
#pragma unroll
        for (int i = 0; i < MI; ++i) {
          int row_l = wm + i * 16 + quad * 4;
          short4v pk;
#pragma unroll
          for (int reg = 0; reg < 4; ++reg) pk[reg] = f2bf(acc[i][j][reg]);
          *(short4v*)(smem + col_l * 136 + row_l) = pk;
        }
      }
      __syncthreads();
#pragma unroll
      for (int it = 0; it < 4; ++it) {
        int idx = it * 256 + tid;
        int col_l = idx >> 4;
        int ch = idx & 15;
        short8v ld = *(const short8v*)(smem + col_l * 136 + ch * 8);
        int col_g = n0 + col_l;
        int hd = col_g / HID;
        int colh = col_g - hd * HID;
        *(short8v*)(Ct + (((long)hd * BB + bb) * HID + colh) * NN + ml0 + ch * 8) = ld;
      }
    }
  }
}

// ---------------------------------------------------------------------------
// Row softmax, nh heads per launch; grid = nh*16384.
// ---------------------------------------------------------------------------
__global__ __launch_bounds__(256) void attn_softmax_kernel(
    const float* __restrict__ Wh1, const float* __restrict__ Wh2,
    const unsigned long long* __restrict__ packed, short* __restrict__ att,
    int head_base) {
  int row = blockIdx.x;
  int hh = row >> 14;
  int rowm = row & 16383;
  int b = rowm >> 11;
  int h = head_base + hh;
  const unsigned char* bits = (const unsigned char*)(packed + (long)rowm * 32);
  const float* wh2b = Wh2 + (long)h * MTOT + b * NN;
  const int t = threadIdx.x;
  const int lane = t & 63;
  const int wv = t >> 6;

  unsigned m8 = bits[t];
  float wh1 = Wh1[(long)h * MTOT + rowm];
  float4 wa = ((const float4*)(wh2b + t * 8))[0];
  float4 wb = ((const float4*)(wh2b + t * 8))[1];
  float v[8] = {wa.x, wa.y, wa.z, wa.w, wb.x, wb.y, wb.z, wb.w};

  float lmax = -INFINITY;
#pragma unroll
  for (int k = 0; k < 8; ++k) {
    float s = wh1 + v[k];
    s = s > 0.f ? s : ALPHA * s;
    s = ((m8 >> k) & 1u) ? s : NEGV;
    v[k] = s;
    lmax = fmaxf(lmax, s);
  }

  __shared__ float redm[4], reds[4];
#pragma unroll
  for (int off = 32; off > 0; off >>= 1) lmax = fmaxf(lmax, __shfl_xor(lmax, off));
  if (lane == 0) redm[wv] = lmax;
  __syncthreads();
  float m = fmaxf(fmaxf(redm[0], redm[1]), fmaxf(redm[2], redm[3]));

  float lsum = 0.f;
#pragma unroll
  for (int k = 0; k < 8; ++k) {
    float p = __expf(v[k] - m);
    v[k] = p;
    lsum += p;
  }
#pragma unroll
  for (int off = 32; off > 0; off >>= 1) lsum += __shfl_xor(lsum, off);
  if (lane == 0) reds[wv] = lsum;
  __syncthreads();
  float inv = 1.f / (reds[0] + reds[1] + reds[2] + reds[3]);

  short8v o;
#pragma unroll
  for (int k = 0; k < 8; ++k) o[k] = f2bf(v[k] * inv);
  *(short8v*)(att + (long)row * NN + t * 8) = o;
}

// ---------------------------------------------------------------------------
extern "C" void kernel_launch(void* const* d_in, const int* in_sizes, int n_in,
                              void* d_out, int out_size, void* d_ws,
                              size_t ws_size, hipStream_t stream) {
  const int* node_feats = (const int*)d_in[0];
  const int* adjs = (const int*)d_in[1];
  const float* embed_table = (const float*)d_in[2];
  const float* W_heads = (const float*)d_in[3];
  const float* a_heads = (const float*)d_in[4];
  const float* W_out = (const float*)d_in[5];
  const float* a_out = (const float*)d_in[6];
  float* out = (float*)d_out;

  // workspace layout (~373 MB)
  char* p = (char*)d_ws;
  short* x_bf = (short*)p;  p += (size_t)MTOT * HID * 2;                 // 25 MB
  short* Wt_h = (short*)p;  p += (size_t)NHEADS * HID * HID * 2;         // 4.7 MB
  short* Wt_o = (short*)p;  p += (size_t)HID * (NHEADS * HID) * 2;       // 4.7 MB
  short* Wh_t = (short*)p;  p += (size_t)NHEADS * BB * HID * NN * 2;     // 100 MB
  short* att2 = (short*)p;  p += (size_t)2 * BB * NN * NN * 2;           // 134 MB
  short* hcat = (short*)p;  p += (size_t)MTOT * NHEADS * HID * 2;        // 100 MB
  unsigned long long* padj = (unsigned long long*)p;
  p += (size_t)BB * NN * NN / 8;                                         // 4.2 MB
  float* Wh1 = (float*)p;   p += (size_t)NHEADS * MTOT * 4;
  float* Wh2 = (float*)p;   p += (size_t)NHEADS * MTOT * 4;
  if ((size_t)(p - (char*)d_ws) > ws_size) return;

  // 0) setup
  transpose_bf16<<<dim3(HID / 32, HID / 32, NHEADS), 256, 0, stream>>>(
      W_heads, Wt_h, HID, HID, (long)HID * HID, (long)HID * HID);
  transpose_bf16<<<dim3((NHEADS * HID) / 32, HID / 32, 1), 256, 0, stream>>>(
      W_out, Wt_o, NHEADS * HID, HID, 0, 0);
  pack_adj_kernel<<<(int)((long)BB * NN * NN / 256), 256, 0, stream>>>(adjs, padj);
  embed_kernel<<<(int)((long)MTOT * HID / 256), 256, 0, stream>>>(
      node_feats, embed_table, x_bf);
  zero_kernel<<<(2 * NHEADS * MTOT + 255) / 256, 256, 0, stream>>>(
      Wh1, 2 * NHEADS * MTOT);

  // 1) all-head projection: x @ [W0|..|W3] -> Wh_t + Wh1/Wh2  (3072 blocks)
  mfma_gemm<128><<<dim3(NHEADS * HID / 128, MTOT / 128, 1), 256, 0, stream>>>(
      x_bf, Wt_h, HID, HID, HID, 0, 0, nullptr, nullptr, 0, 0, Wh_t,
      a_heads, Wh1, Wh2, 0);

  // 2) att layer, two heads at a time
  for (int hb = 0; hb < NHEADS; hb += 2) {
    attn_softmax_kernel<<<2 * MTOT, 256, 0, stream>>>(Wh1, Wh2, padj, att2, hb);
    mfma_gemm<128><<<dim3(HID / 128, NN / 128, 16), 256, 0, stream>>>(
        att2, Wh_t + (long)hb * BB * HID * NN, NN, NN, NN, (long)NN * NN,
        (long)HID * NN, nullptr, hcat + (long)hb * HID, NHEADS * HID,
        (long)NN * NHEADS * HID, nullptr, nullptr, nullptr, nullptr, 1);
  }

  // 3) output GAT layer (zero both layer-2 Wh1/Wh2 slots in one launch)
  zero_kernel<<<(2 * NHEADS * MTOT + 255) / 256, 256, 0, stream>>>(
      Wh1, 2 * NHEADS * MTOT);
  // hcat @ W_out, TN=64 -> 12 x 128 = 1536 blocks (6/CU)
  mfma_gemm<64><<<dim3(HID / 64, MTOT / 128, 1), 256, 0, stream>>>(
      hcat, Wt_o, NHEADS * HID, NHEADS * HID, NHEADS * HID, 0, 0,
      nullptr, nullptr, 0, 0, Wh_t, a_out, Wh1, Wh2, 0);
  attn_softmax_kernel<<<MTOT, 256, 0, stream>>>(Wh1, Wh2, padj, att2, 0);
  // final att @ Who, fused ELU+mean-pool, TN=64 -> 12 x 16 x 8 = 1536 blocks
  zero_kernel<<<(BB * HID + 255) / 256, 256, 0, stream>>>(out, BB * HID);
  mfma_gemm<64><<<dim3(HID / 64, NN / 128, BB), 256, 0, stream>>>(
      att2, Wh_t, NN, NN, NN, (long)NN * NN, (long)HID * NN,
      out, nullptr, 0, 0, nullptr, nullptr, nullptr, nullptr, 3);
}

// Round 7
// 1036.407 us; speedup vs baseline: 1.0068x; 1.0068x over previous
//
#include <hip/hip_runtime.h>
#include <math.h>

#define BB 8
#define NN 2048
#define HID 768
#define NHEADS 4
#define ALPHA 0.2f
#define NEGV -9e15f
#define MTOT (BB * NN)  // 16384

using short4v = __attribute__((ext_vector_type(4))) short;
using short8v = __attribute__((ext_vector_type(8))) short;
using f32x4 = __attribute__((ext_vector_type(4))) float;

__device__ __forceinline__ short f2bf(float f) {
  union { float f; unsigned u; } x;
  x.f = f;
  unsigned r = x.u + 0x7fffu + ((x.u >> 16) & 1u);
  return (short)(r >> 16);
}

__device__ __forceinline__ void cp16(const void* g, void* l) {
  __builtin_amdgcn_global_load_lds(
      (const __attribute__((address_space(1))) unsigned int*)g,
      (__attribute__((address_space(3))) unsigned int*)l, 16, 0, 0);
}

// ---------------------------------------------------------------------------
__global__ __launch_bounds__(256) void embed_kernel(
    const int* __restrict__ nf, const float* __restrict__ table,
    short* __restrict__ x) {
  long idx = (long)blockIdx.x * 256 + threadIdx.x;
  int col = (int)(idx % HID);
  long node = idx / HID;
  x[idx] = f2bf(table[(long)nf[node] * HID + col]);
}

__global__ __launch_bounds__(256) void pack_adj_kernel(
    const int* __restrict__ adj, unsigned long long* __restrict__ packed) {
  long idx = (long)blockIdx.x * 256 + threadIdx.x;
  unsigned long long m = __ballot(adj[idx] > 0);
  if ((threadIdx.x & 63) == 0) packed[idx >> 6] = m;
}

__global__ __launch_bounds__(256) void transpose_bf16(
    const float* __restrict__ W, short* __restrict__ Wt, int K, int N,
    long sIn, long sOut) {
  __shared__ float t[32][33];
  W += (long)blockIdx.z * sIn;
  Wt += (long)blockIdx.z * sOut;
  int k0 = blockIdx.x * 32, n0 = blockIdx.y * 32;
  int tx = threadIdx.x & 31, ty = threadIdx.x >> 5;
#pragma unroll
  for (int i = 0; i < 32; i += 8) t[ty + i][tx] = W[(long)(k0 + ty + i) * N + n0 + tx];
  __syncthreads();
#pragma unroll
  for (int i = 0; i < 32; i += 8)
    Wt[(long)(n0 + ty + i) * K + k0 + tx] = f2bf(t[tx][ty + i]);
}

__global__ __launch_bounds__(256) void zero_kernel(float* __restrict__ p, int n) {
  int i = blockIdx.x * 256 + threadIdx.x;
  if (i < n) p[i] = 0.f;
}

// ---------------------------------------------------------------------------
// bf16 MFMA GEMM, 128x128 tile, BK=64 (two 32-K MFMA substeps per barrier
// pair), XCD swizzle, LDS-repacked epilogues.
// mode 0: Ct bf16 [head][bb][colh][row] via LDS + fused a-dot atomics
// mode 1: Cb bf16 ELU via LDS; z = hh*8+b -> col shift hh*HID
// mode 3: fused ELU + mean-pool: atomicAdd Cf[z*HID + col]
// ---------------------------------------------------------------------------
__global__ __launch_bounds__(256) void mfma_gemm(
    const short* __restrict__ A, const short* __restrict__ B,
    int K, int lda, int ldb, long sA, long sB,
    float* __restrict__ Cf,
    short* __restrict__ Cb, int ldcb, long sCb,
    short* __restrict__ Ct,
    const float* __restrict__ a_vec, float* __restrict__ Wh1g,
    float* __restrict__ Wh2g, int mode) {
  __shared__ short smem[16384];  // As 8192 + Bs 8192 shorts (32 KB); reused
  short* As = smem;
  short* Bs = smem + 8192;

  const int gx = gridDim.x, gy = gridDim.y;
  int lin = blockIdx.x + gx * (blockIdx.y + gy * blockIdx.z);
  const int per = (gx * gy * gridDim.z) >> 3;
  int work = (lin & 7) * per + (lin >> 3);
  const int bx = work % gx;
  int tmp = work / gx;
  const int by = tmp % gy;
  const int z = tmp / gy;

  A += (long)z * sA;
  B += (long)z * sB;

  const int tid = threadIdx.x;
  const int m0 = by * 128;
  const int n0 = bx * 128;

  const int lane = tid & 63;
  const int wid = tid >> 6;
  const int wm = (wid & 1) * 64;
  const int wn = (wid >> 1) * 64;
  const int l15 = lane & 15;
  const int quad = lane >> 4;
  const int sl = l15 & 7;  // read-side chunk swizzle

  f32x4 acc[4][4];
#pragma unroll
  for (int i = 0; i < 4; ++i)
#pragma unroll
    for (int j = 0; j < 4; ++j) acc[i][j] = (f32x4){0.f, 0.f, 0.f, 0.f};

  for (int k0 = 0; k0 < K; k0 += 64) {
    // stage A,B: 128 rows x 64 bf16 (128 B/row = 8 x 16B chunks; slot p
    // holds global chunk p ^ (r&7))
#pragma unroll
    for (int it = 0; it < 4; ++it) {
      int lin2 = it * 256 + tid;  // 0..1023
      int r = lin2 >> 3;
      int p = lin2 & 7;
      int kc = p ^ (r & 7);
      cp16(A + (long)(m0 + r) * lda + k0 + kc * 8, &As[lin2 * 8]);
    }
#pragma unroll
    for (int it = 0; it < 4; ++it) {
      int lin2 = it * 256 + tid;
      int r = lin2 >> 3;
      int p = lin2 & 7;
      int kc = p ^ (r & 7);
      cp16(B + (long)(n0 + r) * ldb + k0 + kc * 8, &Bs[lin2 * 8]);
    }
    __syncthreads();

#pragma unroll
    for (int kk = 0; kk < 2; ++kk) {
      short8v af[4], bfr[4];
#pragma unroll
      for (int i = 0; i < 4; ++i)
        af[i] = *(const short8v*)(As + (wm + i * 16 + l15) * 64 +
                                  (((kk << 2) | quad) ^ sl) * 8);
#pragma unroll
      for (int j = 0; j < 4; ++j)
        bfr[j] = *(const short8v*)(Bs + (wn + j * 16 + l15) * 64 +
                                   (((kk << 2) | quad) ^ sl) * 8);
#pragma unroll
      for (int i = 0; i < 4; ++i)
#pragma unroll
        for (int j = 0; j < 4; ++j)
          acc[i][j] = __builtin_amdgcn_mfma_f32_16x16x32_bf16(af[i], bfr[j],
                                                              acc[i][j], 0, 0, 0);
    }
    __syncthreads();
  }

  // ---- epilogues (C/D layout: col=lane&15 group, row=quad*4+reg) ----
  if (mode == 1) {
    // ELU -> bf16, coalesced via LDS row-major half-tiles (stride 132)
    Cb += (long)(z & 7) * sCb + (long)(z >> 3) * HID;
#pragma unroll
    for (int p = 0; p < 2; ++p) {
      if (wm == p * 64) {
#pragma unroll
        for (int i = 0; i < 4; ++i) {
          int row_l = i * 16 + quad * 4;
#pragma unroll
          for (int j = 0; j < 4; ++j) {
            int col = wn + j * 16 + l15;
#pragma unroll
            for (int reg = 0; reg < 4; ++reg) {
              float v = acc[i][j][reg];
              v = v > 0.f ? v : (__expf(v) - 1.f);
              smem[(row_l + reg) * 132 + col] = f2bf(v);
            }
          }
        }
      }
      __syncthreads();
#pragma unroll
      for (int it = 0; it < 8; ++it) {
        int idx = it * 256 + tid;
        int row_l = idx >> 5;
        int c4 = idx & 31;
        short4v ld = *(const short4v*)(smem + row_l * 132 + c4 * 4);
        *(short4v*)(Cb + (long)(m0 + p * 64 + row_l) * ldcb + n0 + c4 * 4) = ld;
      }
      __syncthreads();
    }
  } else if (mode == 3) {
    // fused ELU + mean-pool: partial col sums -> atomicAdd Cf[z*HID+col]
#pragma unroll
    for (int j = 0; j < 4; ++j) {
      int col = n0 + wn + j * 16 + l15;
      float s = 0.f;
#pragma unroll
      for (int i = 0; i < 4; ++i)
#pragma unroll
        for (int reg = 0; reg < 4; ++reg) {
          float v = acc[i][j][reg];
          s += v > 0.f ? v : (__expf(v) - 1.f);
        }
      s += __shfl_xor(s, 16);
      s += __shfl_xor(s, 32);
      if (quad == 0) atomicAdd(Cf + (long)z * HID + col, s * (1.0f / NN));
    }
  } else {  // mode 0: a-dot + transposed Ct via LDS [col][row] (stride 136)
    float a1v[4], a2v[4];
    const int head0 = (n0 + wn) / HID;  // tiles never straddle head boundary
    {
#pragma unroll
      for (int j = 0; j < 4; ++j) {
        int colh = n0 + wn + j * 16 + l15 - head0 * HID;
        a1v[j] = a_vec[head0 * 2 * HID + colh];
        a2v[j] = a_vec[head0 * 2 * HID + HID + colh];
      }
    }
#pragma unroll
    for (int i = 0; i < 4; ++i) {
      int rb = m0 + wm + i * 16 + quad * 4;
#pragma unroll
      for (int reg = 0; reg < 4; ++reg) {
        float s1 = 0.f, s2 = 0.f;
#pragma unroll
        for (int j = 0; j < 4; ++j) {
          s1 = fmaf(acc[i][j][reg], a1v[j], s1);
          s2 = fmaf(acc[i][j][reg], a2v[j], s2);
        }
#pragma unroll
        for (int off = 1; off < 16; off <<= 1) {
          s1 += __shfl_xor(s1, off);
          s2 += __shfl_xor(s2, off);
        }
        if (l15 == 0) {
          long base = (long)head0 * MTOT + rb + reg;
          atomicAdd(Wh1g + base, s1);
          atomicAdd(Wh2g + base, s2);
        }
      }
    }
    const int bb = m0 >> 11;  // 128-row tile lies within one batch
    const int ml0 = m0 & 2047;
#pragma unroll
    for (int p = 0; p < 2; ++p) {
      if (wn == p * 64) {
#pragma unroll
        for (int j = 0; j < 4; ++j) {
          int col_l = j * 16 + l15;
#pragma unroll
          for (int i = 0; i < 4; ++i) {
            int row_l = wm + i * 16 + quad * 4;
            short4v pk;
#pragma unroll
            for (int reg = 0; reg < 4; ++reg) pk[reg] = f2bf(acc[i][j][reg]);
            *(short4v*)(smem + col_l * 136 + row_l) = pk;
          }
        }
      }
      __syncthreads();
#pragma unroll
      for (int it = 0; it < 4; ++it) {
        int idx = it * 256 + tid;
        int col_l = idx >> 4;
        int ch = idx & 15;
        short8v ld = *(const short8v*)(smem + col_l * 136 + ch * 8);
        int col_g = n0 + p * 64 + col_l;
        int hd = col_g / HID;
        int colh = col_g - hd * HID;
        *(short8v*)(Ct + (((long)hd * BB + bb) * HID + colh) * NN + ml0 + ch * 8) = ld;
      }
      __syncthreads();
    }
  }
}

// ---------------------------------------------------------------------------
// Row softmax, nh heads per launch; grid = nh*16384.
// ---------------------------------------------------------------------------
__global__ __launch_bounds__(256) void attn_softmax_kernel(
    const float* __restrict__ Wh1, const float* __restrict__ Wh2,
    const unsigned long long* __restrict__ packed, short* __restrict__ att,
    int head_base) {
  int row = blockIdx.x;
  int hh = row >> 14;
  int rowm = row & 16383;
  int b = rowm >> 11;
  int h = head_base + hh;
  const unsigned char* bits = (const unsigned char*)(packed + (long)rowm * 32);
  const float* wh2b = Wh2 + (long)h * MTOT + b * NN;
  const int t = threadIdx.x;
  const int lane = t & 63;
  const int wv = t >> 6;

  unsigned m8 = bits[t];
  float wh1 = Wh1[(long)h * MTOT + rowm];
  float4 wa = ((const float4*)(wh2b + t * 8))[0];
  float4 wb = ((const float4*)(wh2b + t * 8))[1];
  float v[8] = {wa.x, wa.y, wa.z, wa.w, wb.x, wb.y, wb.z, wb.w};

  float lmax = -INFINITY;
#pragma unroll
  for (int k = 0; k < 8; ++k) {
    float s = wh1 + v[k];
    s = s > 0.f ? s : ALPHA * s;
    s = ((m8 >> k) & 1u) ? s : NEGV;
    v[k] = s;
    lmax = fmaxf(lmax, s);
  }

  __shared__ float redm[4], reds[4];
#pragma unroll
  for (int off = 32; off > 0; off >>= 1) lmax = fmaxf(lmax, __shfl_xor(lmax, off));
  if (lane == 0) redm[wv] = lmax;
  __syncthreads();
  float m = fmaxf(fmaxf(redm[0], redm[1]), fmaxf(redm[2], redm[3]));

  float lsum = 0.f;
#pragma unroll
  for (int k = 0; k < 8; ++k) {
    float p = __expf(v[k] - m);
    v[k] = p;
    lsum += p;
  }
#pragma unroll
  for (int off = 32; off > 0; off >>= 1) lsum += __shfl_xor(lsum, off);
  if (lane == 0) reds[wv] = lsum;
  __syncthreads();
  float inv = 1.f / (reds[0] + reds[1] + reds[2] + reds[3]);

  short8v o;
#pragma unroll
  for (int k = 0; k < 8; ++k) o[k] = f2bf(v[k] * inv);
  *(short8v*)(att + (long)row * NN + t * 8) = o;
}

// ---------------------------------------------------------------------------
extern "C" void kernel_launch(void* const* d_in, const int* in_sizes, int n_in,
                              void* d_out, int out_size, void* d_ws,
                              size_t ws_size, hipStream_t stream) {
  const int* node_feats = (const int*)d_in[0];
  const int* adjs = (const int*)d_in[1];
  const float* embed_table = (const float*)d_in[2];
  const float* W_heads = (const float*)d_in[3];
  const float* a_heads = (const float*)d_in[4];
  const float* W_out = (const float*)d_in[5];
  const float* a_out = (const float*)d_in[6];
  float* out = (float*)d_out;

  // workspace layout (~373 MB)
  char* p = (char*)d_ws;
  short* x_bf = (short*)p;  p += (size_t)MTOT * HID * 2;                 // 25 MB
  short* Wt_h = (short*)p;  p += (size_t)NHEADS * HID * HID * 2;         // 4.7 MB
  short* Wt_o = (short*)p;  p += (size_t)HID * (NHEADS * HID) * 2;       // 4.7 MB
  short* Wh_t = (short*)p;  p += (size_t)NHEADS * BB * HID * NN * 2;     // 100 MB
  short* att2 = (short*)p;  p += (size_t)2 * BB * NN * NN * 2;           // 134 MB
  short* hcat = (short*)p;  p += (size_t)MTOT * NHEADS * HID * 2;        // 100 MB
  unsigned long long* padj = (unsigned long long*)p;
  p += (size_t)BB * NN * NN / 8;                                         // 4.2 MB
  float* Wh1 = (float*)p;   p += (size_t)NHEADS * MTOT * 4;
  float* Wh2 = (float*)p;   p += (size_t)NHEADS * MTOT * 4;
  if ((size_t)(p - (char*)d_ws) > ws_size) return;

  // 0) setup
  transpose_bf16<<<dim3(HID / 32, HID / 32, NHEADS), 256, 0, stream>>>(
      W_heads, Wt_h, HID, HID, (long)HID * HID, (long)HID * HID);
  transpose_bf16<<<dim3((NHEADS * HID) / 32, HID / 32, 1), 256, 0, stream>>>(
      W_out, Wt_o, NHEADS * HID, HID, 0, 0);
  pack_adj_kernel<<<(int)((long)BB * NN * NN / 256), 256, 0, stream>>>(adjs, padj);
  embed_kernel<<<(int)((long)MTOT * HID / 256), 256, 0, stream>>>(
      node_feats, embed_table, x_bf);
  zero_kernel<<<(2 * NHEADS * MTOT + 255) / 256, 256, 0, stream>>>(
      Wh1, 2 * NHEADS * MTOT);

  // 1) all-head projection: x @ [W0|..|W3] -> Wh_t + Wh1/Wh2  (3072 blocks)
  mfma_gemm<<<dim3(NHEADS * HID / 128, MTOT / 128, 1), 256, 0, stream>>>(
      x_bf, Wt_h, HID, HID, HID, 0, 0, nullptr, nullptr, 0, 0, Wh_t,
      a_heads, Wh1, Wh2, 0);

  // 2) att layer, two heads at a time
  for (int hb = 0; hb < NHEADS; hb += 2) {
    attn_softmax_kernel<<<2 * MTOT, 256, 0, stream>>>(Wh1, Wh2, padj, att2, hb);
    mfma_gemm<<<dim3(HID / 128, NN / 128, 16), 256, 0, stream>>>(
        att2, Wh_t + (long)hb * BB * HID * NN, NN, NN, NN, (long)NN * NN,
        (long)HID * NN, nullptr, hcat + (long)hb * HID, NHEADS * HID,
        (long)NN * NHEADS * HID, nullptr, nullptr, nullptr, nullptr, 1);
  }

  // 3) output GAT layer
  zero_kernel<<<(2 * NHEADS * MTOT + 255) / 256, 256, 0, stream>>>(
      Wh1, 2 * NHEADS * MTOT);
  mfma_gemm<<<dim3(HID / 128, MTOT / 128, 1), 256, 0, stream>>>(
      hcat, Wt_o, NHEADS * HID, NHEADS * HID, NHEADS * HID, 0, 0,
      nullptr, nullptr, 0, 0, Wh_t, a_out, Wh1, Wh2, 0);
  attn_softmax_kernel<<<MTOT, 256, 0, stream>>>(Wh1, Wh2, padj, att2, 0);
  // final att @ Who, fused ELU+mean-pool -> out
  zero_kernel<<<(BB * HID + 255) / 256, 256, 0, stream>>>(out, BB * HID);
  mfma_gemm<<<dim3(HID / 128, NN / 128, BB), 256, 0, stream>>>(
      att2, Wh_t, NN, NN, NN, (long)NN * NN, (long)HID * NN,
      out, nullptr, 0, 0, nullptr, nullptr, nullptr, nullptr, 3);
}

// Round 9
// 928.354 us; speedup vs baseline: 1.1239x; 1.1164x over previous
//
#include <hip/hip_runtime.h>
#include <math.h>

#define BB 8
#define NN 2048
#define HID 768
#define NHEADS 4
#define ALPHA 0.2f
#define NEGV -9e15f
#define MTOT (BB * NN)  // 16384

using short4v = __attribute__((ext_vector_type(4))) short;
using short8v = __attribute__((ext_vector_type(8))) short;
using f32x4 = __attribute__((ext_vector_type(4))) float;

__device__ __forceinline__ short f2bf(float f) {
  union { float f; unsigned u; } x;
  x.f = f;
  unsigned r = x.u + 0x7fffu + ((x.u >> 16) & 1u);
  return (short)(r >> 16);
}

__device__ __forceinline__ void cp16(const void* g, void* l) {
  __builtin_amdgcn_global_load_lds(
      (const __attribute__((address_space(1))) unsigned int*)g,
      (__attribute__((address_space(3))) unsigned int*)l, 16, 0, 0);
}

// ---------------------------------------------------------------------------
__global__ __launch_bounds__(256) void embed_kernel(
    const int* __restrict__ nf, const float* __restrict__ table,
    short* __restrict__ x) {
  long idx = (long)blockIdx.x * 256 + threadIdx.x;
  int col = (int)(idx % HID);
  long node = idx / HID;
  x[idx] = f2bf(table[(long)nf[node] * HID + col]);
}

__global__ __launch_bounds__(256) void pack_adj_kernel(
    const int* __restrict__ adj, unsigned long long* __restrict__ packed) {
  long idx = (long)blockIdx.x * 256 + threadIdx.x;
  unsigned long long m = __ballot(adj[idx] > 0);
  if ((threadIdx.x & 63) == 0) packed[idx >> 6] = m;
}

__global__ __launch_bounds__(256) void transpose_bf16(
    const float* __restrict__ W, short* __restrict__ Wt, int K, int N,
    long sIn, long sOut) {
  __shared__ float t[32][33];
  W += (long)blockIdx.z * sIn;
  Wt += (long)blockIdx.z * sOut;
  int k0 = blockIdx.x * 32, n0 = blockIdx.y * 32;
  int tx = threadIdx.x & 31, ty = threadIdx.x >> 5;
#pragma unroll
  for (int i = 0; i < 32; i += 8) t[ty + i][tx] = W[(long)(k0 + ty + i) * N + n0 + tx];
  __syncthreads();
#pragma unroll
  for (int i = 0; i < 32; i += 8)
    Wt[(long)(n0 + ty + i) * K + k0 + tx] = f2bf(t[tx][ty + i]);
}

__global__ __launch_bounds__(256) void zero_kernel(float* __restrict__ p, int n) {
  int i = blockIdx.x * 256 + threadIdx.x;
  if (i < n) p[i] = 0.f;
}

// ---------------------------------------------------------------------------
// bf16 MFMA GEMM, 128x128 tile, BK=32, XCD swizzle, LDS-repacked epilogues.
// Template MODE kills dead epilogue paths (register high-water mark).
// MODE 0: Ct bf16 [head][bb][colh][row] via LDS + fused a-dot atomics.
//         (fat epilogue -> no occupancy constraint)
// MODE 1: Cb bf16 ELU via LDS; z = hh*8+b -> col shift hh*HID.
//         __launch_bounds__(256,4): 4 blocks/CU.
// MODE 3: fused ELU + mean-pool: atomicAdd Cf[z*HID + col]. Also (256,4).
// ---------------------------------------------------------------------------
template <int MODE>
__global__ __launch_bounds__(256, (MODE == 0) ? 1 : 4) void mfma_gemm(
    const short* __restrict__ A, const short* __restrict__ B,
    int K, int lda, int ldb, long sA, long sB,
    float* __restrict__ Cf,
    short* __restrict__ Cb, int ldcb, long sCb,
    short* __restrict__ Ct,
    const float* __restrict__ a_vec, float* __restrict__ Wh1g,
    float* __restrict__ Wh2g) {
  __shared__ short smem[8704];  // As 4096 + Bs 4096; reused as ctile
  short* As = smem;
  short* Bs = smem + 4096;

  const int gx = gridDim.x, gy = gridDim.y;
  int lin = blockIdx.x + gx * (blockIdx.y + gy * blockIdx.z);
  const int per = (gx * gy * gridDim.z) >> 3;
  int work = (lin & 7) * per + (lin >> 3);
  const int bx = work % gx;
  int tmp = work / gx;
  const int by = tmp % gy;
  const int z = tmp / gy;

  A += (long)z * sA;
  B += (long)z * sB;

  const int tid = threadIdx.x;
  const int m0 = by * 128;
  const int n0 = bx * 128;

  const int lane = tid & 63;
  const int wid = tid >> 6;
  const int wm = (wid & 1) * 64;
  const int wn = (wid >> 1) * 64;
  const int l15 = lane & 15;
  const int quad = lane >> 4;
  const int cp = quad ^ ((l15 >> 1) & 3);

  f32x4 acc[4][4];
#pragma unroll
  for (int i = 0; i < 4; ++i)
#pragma unroll
    for (int j = 0; j < 4; ++j) acc[i][j] = (f32x4){0.f, 0.f, 0.f, 0.f};

  for (int k0 = 0; k0 < K; k0 += 32) {
#pragma unroll
    for (int it = 0; it < 2; ++it) {
      int lin2 = it * 256 + tid;
      int r = lin2 >> 2;
      int p = lin2 & 3;
      int kc = p ^ ((r >> 1) & 3);
      cp16(A + (long)(m0 + r) * lda + k0 + kc * 8, &As[lin2 * 8]);
    }
#pragma unroll
    for (int it = 0; it < 2; ++it) {
      int lin2 = it * 256 + tid;
      int r = lin2 >> 2;
      int p = lin2 & 3;
      int kc = p ^ ((r >> 1) & 3);
      cp16(B + (long)(n0 + r) * ldb + k0 + kc * 8, &Bs[lin2 * 8]);
    }
    __syncthreads();

    short8v af[4], bfr[4];
#pragma unroll
    for (int i = 0; i < 4; ++i)
      af[i] = *(const short8v*)(As + (wm + i * 16 + l15) * 32 + cp * 8);
#pragma unroll
    for (int j = 0; j < 4; ++j)
      bfr[j] = *(const short8v*)(Bs + (wn + j * 16 + l15) * 32 + cp * 8);
#pragma unroll
    for (int i = 0; i < 4; ++i)
#pragma unroll
      for (int j = 0; j < 4; ++j)
        acc[i][j] = __builtin_amdgcn_mfma_f32_16x16x32_bf16(af[i], bfr[j],
                                                            acc[i][j], 0, 0, 0);
    __syncthreads();
  }

  // ---- epilogues (C/D layout: col=lane&15 group, row=quad*4+reg) ----
  if constexpr (MODE == 1) {
    // ELU -> bf16, coalesced via LDS row-major half-tiles (stride 132)
    Cb += (long)(z & 7) * sCb + (long)(z >> 3) * HID;
#pragma unroll
    for (int p = 0; p < 2; ++p) {
      if (wm == p * 64) {
#pragma unroll
        for (int i = 0; i < 4; ++i) {
          int row_l = i * 16 + quad * 4;
#pragma unroll
          for (int j = 0; j < 4; ++j) {
            int col = wn + j * 16 + l15;
#pragma unroll
            for (int reg = 0; reg < 4; ++reg) {
              float v = acc[i][j][reg];
              v = v > 0.f ? v : (__expf(v) - 1.f);
              smem[(row_l + reg) * 132 + col] = f2bf(v);
            }
          }
        }
      }
      __syncthreads();
#pragma unroll
      for (int it = 0; it < 8; ++it) {
        int idx = it * 256 + tid;
        int row_l = idx >> 5;
        int c4 = idx & 31;
        short4v ld = *(const short4v*)(smem + row_l * 132 + c4 * 4);
        *(short4v*)(Cb + (long)(m0 + p * 64 + row_l) * ldcb + n0 + c4 * 4) = ld;
      }
      __syncthreads();
    }
  } else if constexpr (MODE == 3) {
    // fused ELU + mean-pool: partial col sums -> atomicAdd Cf[z*HID+col]
#pragma unroll
    for (int j = 0; j < 4; ++j) {
      int col = n0 + wn + j * 16 + l15;
      float s = 0.f;
#pragma unroll
      for (int i = 0; i < 4; ++i)
#pragma unroll
        for (int reg = 0; reg < 4; ++reg) {
          float v = acc[i][j][reg];
          s += v > 0.f ? v : (__expf(v) - 1.f);
        }
      s += __shfl_xor(s, 16);
      s += __shfl_xor(s, 32);
      if (quad == 0) atomicAdd(Cf + (long)z * HID + col, s * (1.0f / NN));
    }
  } else {  // MODE 0: a-dot + transposed Ct via LDS [col][row] (stride 136)
    float a1v[4], a2v[4];
    const int head0 = (n0 + wn) / HID;  // tiles never straddle head boundary
    {
#pragma unroll
      for (int j = 0; j < 4; ++j) {
        int colh = n0 + wn + j * 16 + l15 - head0 * HID;
        a1v[j] = a_vec[head0 * 2 * HID + colh];
        a2v[j] = a_vec[head0 * 2 * HID + HID + colh];
      }
    }
#pragma unroll
    for (int i = 0; i < 4; ++i) {
      int rb = m0 + wm + i * 16 + quad * 4;
#pragma unroll
      for (int reg = 0; reg < 4; ++reg) {
        float s1 = 0.f, s2 = 0.f;
#pragma unroll
        for (int j = 0; j < 4; ++j) {
          s1 = fmaf(acc[i][j][reg], a1v[j], s1);
          s2 = fmaf(acc[i][j][reg], a2v[j], s2);
        }
#pragma unroll
        for (int off = 1; off < 16; off <<= 1) {
          s1 += __shfl_xor(s1, off);
          s2 += __shfl_xor(s2, off);
        }
        if (l15 == 0) {
          long base = (long)head0 * MTOT + rb + reg;
          atomicAdd(Wh1g + base, s1);
          atomicAdd(Wh2g + base, s2);
        }
      }
    }
    const int bb = m0 >> 11;  // 128-row tile lies within one batch
    const int ml0 = m0 & 2047;
#pragma unroll
    for (int p = 0; p < 2; ++p) {
      if (wn == p * 64) {
#pragma unroll
        for (int j = 0; j < 4; ++j) {
          int col_l = j * 16 + l15;
#pragma unroll
          for (int i = 0; i < 4; ++i) {
            int row_l = wm + i * 16 + quad * 4;
            short4v pk;
#pragma unroll
            for (int reg = 0; reg < 4; ++reg) pk[reg] = f2bf(acc[i][j][reg]);
            *(short4v*)(smem + col_l * 136 + row_l) = pk;
          }
        }
      }
      __syncthreads();
#pragma unroll
      for (int it = 0; it < 4; ++it) {
        int idx = it * 256 + tid;
        int col_l = idx >> 4;
        int ch = idx & 15;
        short8v ld = *(const short8v*)(smem + col_l * 136 + ch * 8);
        int col_g = n0 + p * 64 + col_l;
        int hd = col_g / HID;
        int colh = col_g - hd * HID;
        *(short8v*)(Ct + (((long)hd * BB + bb) * HID + colh) * NN + ml0 + ch * 8) = ld;
      }
      __syncthreads();
    }
  }
}

// ---------------------------------------------------------------------------
// Row softmax, nh heads per launch; grid = nh*16384.
// ---------------------------------------------------------------------------
__global__ __launch_bounds__(256) void attn_softmax_kernel(
    const float* __restrict__ Wh1, const float* __restrict__ Wh2,
    const unsigned long long* __restrict__ packed, short* __restrict__ att,
    int head_base) {
  int row = blockIdx.x;
  int hh = row >> 14;
  int rowm = row & 16383;
  int b = rowm >> 11;
  int h = head_base + hh;
  const unsigned char* bits = (const unsigned char*)(packed + (long)rowm * 32);
  const float* wh2b = Wh2 + (long)h * MTOT + b * NN;
  const int t = threadIdx.x;
  const int lane = t & 63;
  const int wv = t >> 6;

  unsigned m8 = bits[t];
  float wh1 = Wh1[(long)h * MTOT + rowm];
  float4 wa = ((const float4*)(wh2b + t * 8))[0];
  float4 wb = ((const float4*)(wh2b + t * 8))[1];
  float v[8] = {wa.x, wa.y, wa.z, wa.w, wb.x, wb.y, wb.z, wb.w};

  float lmax = -INFINITY;
#pragma unroll
  for (int k = 0; k < 8; ++k) {
    float s = wh1 + v[k];
    s = s > 0.f ? s : ALPHA * s;
    s = ((m8 >> k) & 1u) ? s : NEGV;
    v[k] = s;
    lmax = fmaxf(lmax, s);
  }

  __shared__ float redm[4], reds[4];
#pragma unroll
  for (int off = 32; off > 0; off >>= 1) lmax = fmaxf(lmax, __shfl_xor(lmax, off));
  if (lane == 0) redm[wv] = lmax;
  __syncthreads();
  float m = fmaxf(fmaxf(redm[0], redm[1]), fmaxf(redm[2], redm[3]));

  float lsum = 0.f;
#pragma unroll
  for (int k = 0; k < 8; ++k) {
    float p = __expf(v[k] - m);
    v[k] = p;
    lsum += p;
  }
#pragma unroll
  for (int off = 32; off > 0; off >>= 1) lsum += __shfl_xor(lsum, off);
  if (lane == 0) reds[wv] = lsum;
  __syncthreads();
  float inv = 1.f / (reds[0] + reds[1] + reds[2] + reds[3]);

  short8v o;
#pragma unroll
  for (int k = 0; k < 8; ++k) o[k] = f2bf(v[k] * inv);
  *(short8v*)(att + (long)row * NN + t * 8) = o;
}

// ---------------------------------------------------------------------------
extern "C" void kernel_launch(void* const* d_in, const int* in_sizes, int n_in,
                              void* d_out, int out_size, void* d_ws,
                              size_t ws_size, hipStream_t stream) {
  const int* node_feats = (const int*)d_in[0];
  const int* adjs = (const int*)d_in[1];
  const float* embed_table = (const float*)d_in[2];
  const float* W_heads = (const float*)d_in[3];
  const float* a_heads = (const float*)d_in[4];
  const float* W_out = (const float*)d_in[5];
  const float* a_out = (const float*)d_in[6];
  float* out = (float*)d_out;

  // workspace layout (~373 MB)
  char* p = (char*)d_ws;
  short* x_bf = (short*)p;  p += (size_t)MTOT * HID * 2;                 // 25 MB
  short* Wt_h = (short*)p;  p += (size_t)NHEADS * HID * HID * 2;         // 4.7 MB
  short* Wt_o = (short*)p;  p += (size_t)HID * (NHEADS * HID) * 2;       // 4.7 MB
  short* Wh_t = (short*)p;  p += (size_t)NHEADS * BB * HID * NN * 2;     // 100 MB
  short* att2 = (short*)p;  p += (size_t)2 * BB * NN * NN * 2;           // 134 MB
  short* hcat = (short*)p;  p += (size_t)MTOT * NHEADS * HID * 2;        // 100 MB
  unsigned long long* padj = (unsigned long long*)p;
  p += (size_t)BB * NN * NN / 8;                                         // 4.2 MB
  float* Wh1 = (float*)p;   p += (size_t)NHEADS * MTOT * 4;
  float* Wh2 = (float*)p;   p += (size_t)NHEADS * MTOT * 4;
  if ((size_t)(p - (char*)d_ws) > ws_size) return;

  // 0) setup
  transpose_bf16<<<dim3(HID / 32, HID / 32, NHEADS), 256, 0, stream>>>(
      W_heads, Wt_h, HID, HID, (long)HID * HID, (long)HID * HID);
  transpose_bf16<<<dim3((NHEADS * HID) / 32, HID / 32, 1), 256, 0, stream>>>(
      W_out, Wt_o, NHEADS * HID, HID, 0, 0);
  pack_adj_kernel<<<(int)((long)BB * NN * NN / 256), 256, 0, stream>>>(adjs, padj);
  embed_kernel<<<(int)((long)MTOT * HID / 256), 256, 0, stream>>>(
      node_feats, embed_table, x_bf);
  zero_kernel<<<(2 * NHEADS * MTOT + 255) / 256, 256, 0, stream>>>(
      Wh1, 2 * NHEADS * MTOT);

  // 1) all-head projection: x @ [W0|..|W3] -> Wh_t + Wh1/Wh2  (3072 blocks)
  mfma_gemm<0><<<dim3(NHEADS * HID / 128, MTOT / 128, 1), 256, 0, stream>>>(
      x_bf, Wt_h, HID, HID, HID, 0, 0, nullptr, nullptr, 0, 0, Wh_t,
      a_heads, Wh1, Wh2);

  // 2) att layer, two heads at a time
  for (int hb = 0; hb < NHEADS; hb += 2) {
    attn_softmax_kernel<<<2 * MTOT, 256, 0, stream>>>(Wh1, Wh2, padj, att2, hb);
    mfma_gemm<1><<<dim3(HID / 128, NN / 128, 16), 256, 0, stream>>>(
        att2, Wh_t + (long)hb * BB * HID * NN, NN, NN, NN, (long)NN * NN,
        (long)HID * NN, nullptr, hcat + (long)hb * HID, NHEADS * HID,
        (long)NN * NHEADS * HID, nullptr, nullptr, nullptr, nullptr);
  }

  // 3) output GAT layer
  zero_kernel<<<(2 * NHEADS * MTOT + 255) / 256, 256, 0, stream>>>(
      Wh1, 2 * NHEADS * MTOT);
  mfma_gemm<0><<<dim3(HID / 128, MTOT / 128, 1), 256, 0, stream>>>(
      hcat, Wt_o, NHEADS * HID, NHEADS * HID, NHEADS * HID, 0, 0,
      nullptr, nullptr, 0, 0, Wh_t, a_out, Wh1, Wh2);
  attn_softmax_kernel<<<MTOT, 256, 0, stream>>>(Wh1, Wh2, padj, att2, 0);
  // final att @ Who, fused ELU+mean-pool -> out
  zero_kernel<<<(BB * HID + 255) / 256, 256, 0, stream>>>(out, BB * HID);
  mfma_gemm<3><<<dim3(HID / 128, NN / 128, BB), 256, 0, stream>>>(
      att2, Wh_t, NN, NN, NN, (long)NN * NN, (long)HID * NN,
      out, nullptr, 0, 0, nullptr, nullptr, nullptr, nullptr);
}

// Round 10
// 882.858 us; speedup vs baseline: 1.1819x; 1.0515x over previous
//
#include <hip/hip_runtime.h>
#include <math.h>

#define BB 8
#define NN 2048
#define HID 768
#define NHEADS 4
#define ALPHA 0.2f
#define NEGV -9e15f
#define MTOT (BB * NN)  // 16384

using short4v = __attribute__((ext_vector_type(4))) short;
using short8v = __attribute__((ext_vector_type(8))) short;
using f32x4 = __attribute__((ext_vector_type(4))) float;

__device__ __forceinline__ short f2bf(float f) {
  union { float f; unsigned u; } x;
  x.f = f;
  unsigned r = x.u + 0x7fffu + ((x.u >> 16) & 1u);
  return (short)(r >> 16);
}

__device__ __forceinline__ void cp16(const void* g, void* l) {
  __builtin_amdgcn_global_load_lds(
      (const __attribute__((address_space(1))) unsigned int*)g,
      (__attribute__((address_space(3))) unsigned int*)l, 16, 0, 0);
}

// ---------------------------------------------------------------------------
// All weight transposes in one launch. z<4: W_heads head z (768x768).
// z==4: W_out (3072x768). Wt[n][k] = bf16(W[k][n]).
// ---------------------------------------------------------------------------
__global__ __launch_bounds__(256) void transpose_all(
    const float* __restrict__ W_heads, const float* __restrict__ W_out,
    short* __restrict__ Wt_h, short* __restrict__ Wt_o) {
  const int z = blockIdx.z;
  const float* W;
  short* Wt;
  int K, N;
  if (z < 4) {
    if (blockIdx.x >= 24) return;  // 768/32 tiles in k
    W = W_heads + (long)z * HID * HID;
    Wt = Wt_h + (long)z * HID * HID;
    K = HID;
    N = HID;
  } else {
    W = W_out;
    Wt = Wt_o;
    K = NHEADS * HID;
    N = HID;
  }
  __shared__ float t[32][33];
  int k0 = blockIdx.x * 32, n0 = blockIdx.y * 32;
  int tx = threadIdx.x & 31, ty = threadIdx.x >> 5;
#pragma unroll
  for (int i = 0; i < 32; i += 8) t[ty + i][tx] = W[(long)(k0 + ty + i) * N + n0 + tx];
  __syncthreads();
#pragma unroll
  for (int i = 0; i < 32; i += 8)
    Wt[(long)(n0 + ty + i) * K + k0 + tx] = f2bf(t[tx][ty + i]);
}

// ---------------------------------------------------------------------------
// Fused setup: [0,131072) adjacency bit-pack; [131072,180224) embedding;
// [180224,180736) zero Wh1/Wh2 (131072 floats).
// ---------------------------------------------------------------------------
#define PACK_B 131072
#define EMB_B 49152
#define ZERO_B 512
__global__ __launch_bounds__(256) void setup_kernel(
    const int* __restrict__ adj, unsigned long long* __restrict__ packed,
    const int* __restrict__ nf, const float* __restrict__ table,
    short* __restrict__ x, float* __restrict__ wh12) {
  const int bid = blockIdx.x;
  const int tid = threadIdx.x;
  if (bid < PACK_B) {
    long idx = (long)bid * 256 + tid;
    unsigned long long m = __ballot(adj[idx] > 0);
    if ((tid & 63) == 0) packed[idx >> 6] = m;
  } else if (bid < PACK_B + EMB_B) {
    long idx = (long)(bid - PACK_B) * 256 + tid;
    int col = (int)(idx % HID);
    long node = idx / HID;
    x[idx] = f2bf(table[(long)nf[node] * HID + col]);
  } else {
    int i = (bid - PACK_B - EMB_B) * 256 + tid;
    wh12[i] = 0.f;
  }
}

// ---------------------------------------------------------------------------
// bf16 MFMA GEMM, 128x128 tile, BK=32, XCD swizzle, LDS-repacked epilogues.
// __launch_bounds__(256,4) on ALL modes (mode-1 evidence: VGPR 56, +15%).
// MODE 0: Ct bf16 [head][bb][colh][row] via LDS + fused a-dot atomics.
// MODE 1: Cb bf16 ELU via LDS; z = hh*8+b -> col shift hh*HID.
// MODE 3: fused ELU + mean-pool: atomicAdd Cf[z*HID + col].
// ---------------------------------------------------------------------------
template <int MODE>
__global__ __launch_bounds__(256, 4) void mfma_gemm(
    const short* __restrict__ A, const short* __restrict__ B,
    int K, int lda, int ldb, long sA, long sB,
    float* __restrict__ Cf,
    short* __restrict__ Cb, int ldcb, long sCb,
    short* __restrict__ Ct,
    const float* __restrict__ a_vec, float* __restrict__ Wh1g,
    float* __restrict__ Wh2g) {
  __shared__ short smem[8704];  // As 4096 + Bs 4096; reused as ctile
  short* As = smem;
  short* Bs = smem + 4096;

  const int gx = gridDim.x, gy = gridDim.y;
  int lin = blockIdx.x + gx * (blockIdx.y + gy * blockIdx.z);
  const int per = (gx * gy * gridDim.z) >> 3;
  int work = (lin & 7) * per + (lin >> 3);
  const int bx = work % gx;
  int tmp = work / gx;
  const int by = tmp % gy;
  const int z = tmp / gy;

  A += (long)z * sA;
  B += (long)z * sB;

  const int tid = threadIdx.x;
  const int m0 = by * 128;
  const int n0 = bx * 128;

  const int lane = tid & 63;
  const int wid = tid >> 6;
  const int wm = (wid & 1) * 64;
  const int wn = (wid >> 1) * 64;
  const int l15 = lane & 15;
  const int quad = lane >> 4;
  const int cp = quad ^ ((l15 >> 1) & 3);

  f32x4 acc[4][4];
#pragma unroll
  for (int i = 0; i < 4; ++i)
#pragma unroll
    for (int j = 0; j < 4; ++j) acc[i][j] = (f32x4){0.f, 0.f, 0.f, 0.f};

  for (int k0 = 0; k0 < K; k0 += 32) {
#pragma unroll
    for (int it = 0; it < 2; ++it) {
      int lin2 = it * 256 + tid;
      int r = lin2 >> 2;
      int p = lin2 & 3;
      int kc = p ^ ((r >> 1) & 3);
      cp16(A + (long)(m0 + r) * lda + k0 + kc * 8, &As[lin2 * 8]);
    }
#pragma unroll
    for (int it = 0; it < 2; ++it) {
      int lin2 = it * 256 + tid;
      int r = lin2 >> 2;
      int p = lin2 & 3;
      int kc = p ^ ((r >> 1) & 3);
      cp16(B + (long)(n0 + r) * ldb + k0 + kc * 8, &Bs[lin2 * 8]);
    }
    __syncthreads();

    short8v af[4], bfr[4];
#pragma unroll
    for (int i = 0; i < 4; ++i)
      af[i] = *(const short8v*)(As + (wm + i * 16 + l15) * 32 + cp * 8);
#pragma unroll
    for (int j = 0; j < 4; ++j)
      bfr[j] = *(const short8v*)(Bs + (wn + j * 16 + l15) * 32 + cp * 8);
#pragma unroll
    for (int i = 0; i < 4; ++i)
#pragma unroll
      for (int j = 0; j < 4; ++j)
        acc[i][j] = __builtin_amdgcn_mfma_f32_16x16x32_bf16(af[i], bfr[j],
                                                            acc[i][j], 0, 0, 0);
    __syncthreads();
  }

  // ---- epilogues (C/D layout: col=lane&15 group, row=quad*4+reg) ----
  if constexpr (MODE == 1) {
    // ELU -> bf16, coalesced via LDS row-major half-tiles (stride 132)
    Cb += (long)(z & 7) * sCb + (long)(z >> 3) * HID;
#pragma unroll
    for (int p = 0; p < 2; ++p) {
      if (wm == p * 64) {
#pragma unroll
        for (int i = 0; i < 4; ++i) {
          int row_l = i * 16 + quad * 4;
#pragma unroll
          for (int j = 0; j < 4; ++j) {
            int col = wn + j * 16 + l15;
#pragma unroll
            for (int reg = 0; reg < 4; ++reg) {
              float v = acc[i][j][reg];
              v = v > 0.f ? v : (__expf(v) - 1.f);
              smem[(row_l + reg) * 132 + col] = f2bf(v);
            }
          }
        }
      }
      __syncthreads();
#pragma unroll
      for (int it = 0; it < 8; ++it) {
        int idx = it * 256 + tid;
        int row_l = idx >> 5;
        int c4 = idx & 31;
        short4v ld = *(const short4v*)(smem + row_l * 132 + c4 * 4);
        *(short4v*)(Cb + (long)(m0 + p * 64 + row_l) * ldcb + n0 + c4 * 4) = ld;
      }
      __syncthreads();
    }
  } else if constexpr (MODE == 3) {
    // fused ELU + mean-pool: partial col sums -> atomicAdd Cf[z*HID+col]
#pragma unroll
    for (int j = 0; j < 4; ++j) {
      int col = n0 + wn + j * 16 + l15;
      float s = 0.f;
#pragma unroll
      for (int i = 0; i < 4; ++i)
#pragma unroll
        for (int reg = 0; reg < 4; ++reg) {
          float v = acc[i][j][reg];
          s += v > 0.f ? v : (__expf(v) - 1.f);
        }
      s += __shfl_xor(s, 16);
      s += __shfl_xor(s, 32);
      if (quad == 0) atomicAdd(Cf + (long)z * HID + col, s * (1.0f / NN));
    }
  } else {  // MODE 0: a-dot + transposed Ct via LDS [col][row] (stride 136)
    float a1v[4], a2v[4];
    const int head0 = (n0 + wn) / HID;  // tiles never straddle head boundary
    {
#pragma unroll
      for (int j = 0; j < 4; ++j) {
        int colh = n0 + wn + j * 16 + l15 - head0 * HID;
        a1v[j] = a_vec[head0 * 2 * HID + colh];
        a2v[j] = a_vec[head0 * 2 * HID + HID + colh];
      }
    }
#pragma unroll
    for (int i = 0; i < 4; ++i) {
      int rb = m0 + wm + i * 16 + quad * 4;
#pragma unroll
      for (int reg = 0; reg < 4; ++reg) {
        float s1 = 0.f, s2 = 0.f;
#pragma unroll
        for (int j = 0; j < 4; ++j) {
          s1 = fmaf(acc[i][j][reg], a1v[j], s1);
          s2 = fmaf(acc[i][j][reg], a2v[j], s2);
        }
#pragma unroll
        for (int off = 1; off < 16; off <<= 1) {
          s1 += __shfl_xor(s1, off);
          s2 += __shfl_xor(s2, off);
        }
        if (l15 == 0) {
          long base = (long)head0 * MTOT + rb + reg;
          atomicAdd(Wh1g + base, s1);
          atomicAdd(Wh2g + base, s2);
        }
      }
    }
    const int bb = m0 >> 11;  // 128-row tile lies within one batch
    const int ml0 = m0 & 2047;
#pragma unroll
    for (int p = 0; p < 2; ++p) {
      if (wn == p * 64) {
#pragma unroll
        for (int j = 0; j < 4; ++j) {
          int col_l = j * 16 + l15;
#pragma unroll
          for (int i = 0; i < 4; ++i) {
            int row_l = wm + i * 16 + quad * 4;
            short4v pk;
#pragma unroll
            for (int reg = 0; reg < 4; ++reg) pk[reg] = f2bf(acc[i][j][reg]);
            *(short4v*)(smem + col_l * 136 + row_l) = pk;
          }
        }
      }
      __syncthreads();
#pragma unroll
      for (int it = 0; it < 4; ++it) {
        int idx = it * 256 + tid;
        int col_l = idx >> 4;
        int ch = idx & 15;
        short8v ld = *(const short8v*)(smem + col_l * 136 + ch * 8);
        int col_g = n0 + p * 64 + col_l;
        int hd = col_g / HID;
        int colh = col_g - hd * HID;
        *(short8v*)(Ct + (((long)hd * BB + bb) * HID + colh) * NN + ml0 + ch * 8) = ld;
      }
      __syncthreads();
    }
  }
}

// ---------------------------------------------------------------------------
// Row softmax, nh heads per launch; grid = nh*16384. Optional fused zeroing:
// blocks [0,zn) additionally zero zA[b*256+t] (and zB if non-null) — used to
// clear the next stage's atomic accumulators / output (write-disjoint from
// this launch's reads; stream-ordered before consumers).
// ---------------------------------------------------------------------------
__global__ __launch_bounds__(256) void attn_softmax_kernel(
    const float* __restrict__ Wh1, const float* __restrict__ Wh2,
    const unsigned long long* __restrict__ packed, short* __restrict__ att,
    int head_base, float* __restrict__ zA, float* __restrict__ zB, int zn) {
  int row = blockIdx.x;
  if (row < zn) {
    zA[row * 256 + threadIdx.x] = 0.f;
    if (zB) zB[row * 256 + threadIdx.x] = 0.f;
  }
  int hh = row >> 14;
  int rowm = row & 16383;
  int b = rowm >> 11;
  int h = head_base + hh;
  const unsigned char* bits = (const unsigned char*)(packed + (long)rowm * 32);
  const float* wh2b = Wh2 + (long)h * MTOT + b * NN;
  const int t = threadIdx.x;
  const int lane = t & 63;
  const int wv = t >> 6;

  unsigned m8 = bits[t];
  float wh1 = Wh1[(long)h * MTOT + rowm];
  float4 wa = ((const float4*)(wh2b + t * 8))[0];
  float4 wb = ((const float4*)(wh2b + t * 8))[1];
  float v[8] = {wa.x, wa.y, wa.z, wa.w, wb.x, wb.y, wb.z, wb.w};

  float lmax = -INFINITY;
#pragma unroll
  for (int k = 0; k < 8; ++k) {
    float s = wh1 + v[k];
    s = s > 0.f ? s : ALPHA * s;
    s = ((m8 >> k) & 1u) ? s : NEGV;
    v[k] = s;
    lmax = fmaxf(lmax, s);
  }

  __shared__ float redm[4], reds[4];
#pragma unroll
  for (int off = 32; off > 0; off >>= 1) lmax = fmaxf(lmax, __shfl_xor(lmax, off));
  if (lane == 0) redm[wv] = lmax;
  __syncthreads();
  float m = fmaxf(fmaxf(redm[0], redm[1]), fmaxf(redm[2], redm[3]));

  float lsum = 0.f;
#pragma unroll
  for (int k = 0; k < 8; ++k) {
    float p = __expf(v[k] - m);
    v[k] = p;
    lsum += p;
  }
#pragma unroll
  for (int off = 32; off > 0; off >>= 1) lsum += __shfl_xor(lsum, off);
  if (lane == 0) reds[wv] = lsum;
  __syncthreads();
  float inv = 1.f / (reds[0] + reds[1] + reds[2] + reds[3]);

  short8v o;
#pragma unroll
  for (int k = 0; k < 8; ++k) o[k] = f2bf(v[k] * inv);
  *(short8v*)(att + (long)row * NN + t * 8) = o;
}

// ---------------------------------------------------------------------------
extern "C" void kernel_launch(void* const* d_in, const int* in_sizes, int n_in,
                              void* d_out, int out_size, void* d_ws,
                              size_t ws_size, hipStream_t stream) {
  const int* node_feats = (const int*)d_in[0];
  const int* adjs = (const int*)d_in[1];
  const float* embed_table = (const float*)d_in[2];
  const float* W_heads = (const float*)d_in[3];
  const float* a_heads = (const float*)d_in[4];
  const float* W_out = (const float*)d_in[5];
  const float* a_out = (const float*)d_in[6];
  float* out = (float*)d_out;

  // workspace layout (~373 MB)
  char* p = (char*)d_ws;
  short* x_bf = (short*)p;  p += (size_t)MTOT * HID * 2;                 // 25 MB
  short* Wt_h = (short*)p;  p += (size_t)NHEADS * HID * HID * 2;         // 4.7 MB
  short* Wt_o = (short*)p;  p += (size_t)HID * (NHEADS * HID) * 2;       // 4.7 MB
  short* Wh_t = (short*)p;  p += (size_t)NHEADS * BB * HID * NN * 2;     // 100 MB
  short* att2 = (short*)p;  p += (size_t)2 * BB * NN * NN * 2;           // 134 MB
  short* hcat = (short*)p;  p += (size_t)MTOT * NHEADS * HID * 2;        // 100 MB
  unsigned long long* padj = (unsigned long long*)p;
  p += (size_t)BB * NN * NN / 8;                                         // 4.2 MB
  float* Wh1 = (float*)p;   p += (size_t)NHEADS * MTOT * 4;
  float* Wh2 = (float*)p;   p += (size_t)NHEADS * MTOT * 4;
  if ((size_t)(p - (char*)d_ws) > ws_size) return;

  // 0) setup (2 launches): all transposes; pack+embed+zero
  transpose_all<<<dim3(96, 24, 5), 256, 0, stream>>>(W_heads, W_out, Wt_h,
                                                     Wt_o);
  setup_kernel<<<PACK_B + EMB_B + ZERO_B, 256, 0, stream>>>(
      adjs, padj, node_feats, embed_table, x_bf, Wh1);

  // 1) all-head projection: x @ [W0|..|W3] -> Wh_t + Wh1/Wh2  (3072 blocks)
  mfma_gemm<0><<<dim3(NHEADS * HID / 128, MTOT / 128, 1), 256, 0, stream>>>(
      x_bf, Wt_h, HID, HID, HID, 0, 0, nullptr, nullptr, 0, 0, Wh_t,
      a_heads, Wh1, Wh2);

  // 2) att layer, two heads at a time. hb=2 softmax also zeros the layer-2
  //    Wh1/Wh2 head-0 slots (disjoint from its reads at slots 2,3).
  attn_softmax_kernel<<<2 * MTOT, 256, 0, stream>>>(Wh1, Wh2, padj, att2, 0,
                                                    nullptr, nullptr, 0);
  mfma_gemm<1><<<dim3(HID / 128, NN / 128, 16), 256, 0, stream>>>(
      att2, Wh_t, NN, NN, NN, (long)NN * NN, (long)HID * NN, nullptr, hcat,
      NHEADS * HID, (long)NN * NHEADS * HID, nullptr, nullptr, nullptr,
      nullptr);
  attn_softmax_kernel<<<2 * MTOT, 256, 0, stream>>>(Wh1, Wh2, padj, att2, 2,
                                                    Wh1, Wh2, 64);
  mfma_gemm<1><<<dim3(HID / 128, NN / 128, 16), 256, 0, stream>>>(
      att2, Wh_t + (long)2 * BB * HID * NN, NN, NN, NN, (long)NN * NN,
      (long)HID * NN, nullptr, hcat + (long)2 * HID, NHEADS * HID,
      (long)NN * NHEADS * HID, nullptr, nullptr, nullptr, nullptr);

  // 3) output GAT layer. L2 softmax also zeros `out` (24 blocks x 256).
  mfma_gemm<0><<<dim3(HID / 128, MTOT / 128, 1), 256, 0, stream>>>(
      hcat, Wt_o, NHEADS * HID, NHEADS * HID, NHEADS * HID, 0, 0,
      nullptr, nullptr, 0, 0, Wh_t, a_out, Wh1, Wh2);
  attn_softmax_kernel<<<MTOT, 256, 0, stream>>>(Wh1, Wh2, padj, att2, 0, out,
                                                nullptr, 24);
  mfma_gemm<3><<<dim3(HID / 128, NN / 128, BB), 256, 0, stream>>>(
      att2, Wh_t, NN, NN, NN, (long)NN * NN, (long)HID * NN,
      out, nullptr, 0, 0, nullptr, nullptr, nullptr, nullptr);
}

// Round 11
// 682.369 us; speedup vs baseline: 1.5291x; 1.2938x over previous
//
#include <hip/hip_runtime.h>
#include <math.h>

#define BB 8
#define NN 2048
#define HID 768
#define NHEADS 4
#define VOCAB 15
#define ALPHA 0.2f
#define NEGV -9e15f
#define MTOT (BB * NN)  // 16384

using short4v = __attribute__((ext_vector_type(4))) short;
using short8v = __attribute__((ext_vector_type(8))) short;
using f32x4 = __attribute__((ext_vector_type(4))) float;

__device__ __forceinline__ short f2bf(float f) {
  union { float f; unsigned u; } x;
  x.f = f;
  unsigned r = x.u + 0x7fffu + ((x.u >> 16) & 1u);
  return (short)(r >> 16);
}

__device__ __forceinline__ void cp16(const void* g, void* l) {
  __builtin_amdgcn_global_load_lds(
      (const __attribute__((address_space(1))) unsigned int*)g,
      (__attribute__((address_space(3))) unsigned int*)l, 16, 0, 0);
}

// ---------------------------------------------------------------------------
// W_out transpose -> bf16 [n][k] (3072x768 -> 768x3072)
// ---------------------------------------------------------------------------
__global__ __launch_bounds__(256) void transpose_o(
    const float* __restrict__ W, short* __restrict__ Wt) {
  __shared__ float t[32][33];
  const int K = NHEADS * HID, N = HID;
  int k0 = blockIdx.x * 32, n0 = blockIdx.y * 32;
  int tx = threadIdx.x & 31, ty = threadIdx.x >> 5;
#pragma unroll
  for (int i = 0; i < 32; i += 8) t[ty + i][tx] = W[(long)(k0 + ty + i) * N + n0 + tx];
  __syncthreads();
#pragma unroll
  for (int i = 0; i < 32; i += 8)
    Wt[(long)(n0 + ty + i) * K + k0 + tx] = f2bf(t[tx][ty + i]);
}

// ---------------------------------------------------------------------------
// Fused setup: [0,131072) adjacency bit-pack; [131072,131380) zero the
// contiguous {Wh1,Wh2,TW} region (78848 floats = 308 blocks).
// ---------------------------------------------------------------------------
#define PACK_B 131072
#define ZERO_B 308
__global__ __launch_bounds__(256) void setup_kernel(
    const int* __restrict__ adj, unsigned long long* __restrict__ packed,
    float* __restrict__ zbase) {
  const int bid = blockIdx.x;
  const int tid = threadIdx.x;
  if (bid < PACK_B) {
    long idx = (long)bid * 256 + tid;
    unsigned long long m = __ballot(adj[idx] > 0);
    if ((tid & 63) == 0) packed[idx >> 6] = m;
  } else {
    zbase[(bid - PACK_B) * 256 + tid] = 0.f;
  }
}

// ---------------------------------------------------------------------------
// TW[v][c] = sum_k table[v][k] * W_heads[h(c)][k][n(c)]  (fp32, 15 x 3072)
// grid (12, 4): x -> 256-col chunk (within one head), y -> k-chunk of 192.
// Partial sums accumulated with atomicAdd (TW pre-zeroed by setup).
// ---------------------------------------------------------------------------
__global__ __launch_bounds__(256) void tw_kernel(
    const float* __restrict__ table, const float* __restrict__ W_heads,
    float* __restrict__ TW) {
  __shared__ float tbl[VOCAB][192];
  const int c = blockIdx.x * 256 + threadIdx.x;  // 0..3071
  const int h = (blockIdx.x * 256) / HID;        // uniform per block
  const int n = c - h * HID;
  const int k0 = blockIdx.y * 192;
  for (int idx = threadIdx.x; idx < VOCAB * 192; idx += 256)
    tbl[idx / 192][idx % 192] = table[(idx / 192) * HID + k0 + idx % 192];
  __syncthreads();
  float acc[VOCAB];
#pragma unroll
  for (int v = 0; v < VOCAB; ++v) acc[v] = 0.f;
  for (int kk = 0; kk < 192; ++kk) {
    float w = W_heads[(long)h * HID * HID + (long)(k0 + kk) * HID + n];
#pragma unroll
    for (int v = 0; v < VOCAB; ++v) acc[v] = fmaf(tbl[v][kk], w, acc[v]);
  }
#pragma unroll
  for (int v = 0; v < VOCAB; ++v) atomicAdd(&TW[v * (NHEADS * HID) + c], acc[v]);
}

// ---------------------------------------------------------------------------
// TW1[h][v] = TW[v][h*HID:] . a1_h ; TW2 likewise with a2_h. grid 60 blocks.
// ---------------------------------------------------------------------------
__global__ __launch_bounds__(256) void tw12_kernel(
    const float* __restrict__ TW, const float* __restrict__ a_heads,
    float* __restrict__ TW1, float* __restrict__ TW2) {
  int h = blockIdx.x / VOCAB, v = blockIdx.x % VOCAB;
  const float* twr = TW + v * (NHEADS * HID) + h * HID;
  const float* a1 = a_heads + h * 2 * HID;
  float s1 = 0.f, s2 = 0.f;
  for (int n = threadIdx.x; n < HID; n += 256) {
    float t = twr[n];
    s1 = fmaf(t, a1[n], s1);
    s2 = fmaf(t, a1[HID + n], s2);
  }
  __shared__ float r1[256], r2[256];
  r1[threadIdx.x] = s1;
  r2[threadIdx.x] = s2;
  __syncthreads();
  for (int s = 128; s > 0; s >>= 1) {
    if (threadIdx.x < s) {
      r1[threadIdx.x] += r1[threadIdx.x + s];
      r2[threadIdx.x] += r2[threadIdx.x + s];
    }
    __syncthreads();
  }
  if (threadIdx.x == 0) {
    TW1[h * VOCAB + v] = r1[0];
    TW2[h * VOCAB + v] = r2[0];
  }
}

// ---------------------------------------------------------------------------
// Layer-1 bucket softmax: per (h,row) compute masked-softmax over 2048 cols
// and directly accumulate P[i][v] = sum_{j: nf[j]=v} att[i][j] (15 buckets).
// Never materializes att. grid = 4*16384. Output P16 [h][rowm][16] fp32.
// ---------------------------------------------------------------------------
__global__ __launch_bounds__(256) void bucket_softmax(
    const int* __restrict__ nf, const unsigned long long* __restrict__ packed,
    const float* __restrict__ TW1, const float* __restrict__ TW2,
    float* __restrict__ P16) {
  const int blk = blockIdx.x;
  const int h = blk >> 14;
  const int rowm = blk & 16383;
  const int b = rowm >> 11;
  const int i = rowm & 2047;
  const int t = threadIdx.x;
  const int lane = t & 63;
  const int wv = t >> 6;

  __shared__ float hist[4096];
  __shared__ float tw1s[VOCAB], tw2s[VOCAB];
  __shared__ float redm[4], reds[4];
  if (t < VOCAB) tw1s[t] = TW1[h * VOCAB + t];
  else if (t < 2 * VOCAB) tw2s[t - VOCAB] = TW2[h * VOCAB + t - VOCAB];

  int4 na = *(const int4*)(nf + b * NN + t * 8);
  int4 nb = *(const int4*)(nf + b * NN + t * 8 + 4);
  int nf8[8] = {na.x, na.y, na.z, na.w, nb.x, nb.y, nb.z, nb.w};
  unsigned m8 = ((const unsigned char*)(packed + (long)rowm * 32))[t];
  int nfi = nf[b * NN + i];  // wave-uniform broadcast
  __syncthreads();

  float wh1 = tw1s[nfi];
  float v[8];
  float lmax = -INFINITY;
#pragma unroll
  for (int k = 0; k < 8; ++k) {
    float s = wh1 + tw2s[nf8[k]];
    s = s > 0.f ? s : ALPHA * s;
    s = ((m8 >> k) & 1u) ? s : NEGV;
    v[k] = s;
    lmax = fmaxf(lmax, s);
  }
#pragma unroll
  for (int off = 32; off > 0; off >>= 1) lmax = fmaxf(lmax, __shfl_xor(lmax, off));
  if (lane == 0) redm[wv] = lmax;
  __syncthreads();
  float m = fmaxf(fmaxf(redm[0], redm[1]), fmaxf(redm[2], redm[3]));

  float lsum = 0.f;
#pragma unroll
  for (int k = 0; k < 8; ++k) {
    float p = __expf(v[k] - m);
    v[k] = p;
    lsum += p;
  }
#pragma unroll
  for (int off = 32; off > 0; off >>= 1) lsum += __shfl_xor(lsum, off);
  if (lane == 0) reds[wv] = lsum;
  __syncthreads();
  float inv = 1.f / (reds[0] + reds[1] + reds[2] + reds[3]);

  // bucket accumulate into private LDS row, then cross-thread tree-reduce
#pragma unroll
  for (int vv = 0; vv < 16; ++vv) hist[t * 16 + vv] = 0.f;
#pragma unroll
  for (int k = 0; k < 8; ++k) hist[t * 16 + nf8[k]] += v[k];
  __syncthreads();
  for (int s = 128; s >= 1; s >>= 1) {
    for (int rr = t; rr < 16 * s; rr += 256) hist[rr] += hist[rr + 16 * s];
    __syncthreads();
  }
  if (t < VOCAB) P16[((long)h * 16384 + rowm) * 16 + t] = hist[t] * inv;
}

// ---------------------------------------------------------------------------
// hcat[r][h*HID+colh] = ELU( sum_v P16[h][r][v] * TW[v][h*HID+colh] ) -> bf16
// grid (24, 128): 128-col x 128-row tiles (col chunks align within heads).
// ---------------------------------------------------------------------------
__global__ __launch_bounds__(256) void hcat_expand(
    const float* __restrict__ TW, const float* __restrict__ P16,
    short* __restrict__ hcat) {
  __shared__ float twl[VOCAB * 128];
  __shared__ float pl[128 * 16];
  const int c0 = blockIdx.x * 128;
  const int r0 = blockIdx.y * 128;
  const int h = c0 / HID;
  const int t = threadIdx.x;
  for (int idx = t; idx < VOCAB * 128; idx += 256)
    twl[idx] = TW[(idx / 128) * (NHEADS * HID) + c0 + (idx & 127)];
  for (int idx = t; idx < 128 * 16; idx += 256)
    pl[idx] = P16[((long)h * 16384 + r0 + (idx >> 4)) * 16 + (idx & 15)];
  __syncthreads();
  const int clb = (t & 31) * 4;
  const int rlb = (t >> 5) * 16;
#pragma unroll 4
  for (int rr = 0; rr < 16; ++rr) {
    int rl = rlb + rr;
    short4v o;
#pragma unroll
    for (int cc = 0; cc < 4; ++cc) {
      float s = 0.f;
#pragma unroll
      for (int vv = 0; vv < VOCAB; ++vv)
        s = fmaf(pl[rl * 16 + vv], twl[vv * 128 + clb + cc], s);
      s = s > 0.f ? s : (__expf(s) - 1.f);
      o[cc] = f2bf(s);
    }
    *(short4v*)(hcat + (long)(r0 + rl) * (NHEADS * HID) + c0 + clb) = o;
  }
}

// ---------------------------------------------------------------------------
// bf16 MFMA GEMM, 128x128 tile, BK=32, XCD swizzle, LDS-repacked epilogues.
// MODE 0: Ct bf16 [bb][colh][row] via LDS + fused a-dot atomics (layer 2).
// MODE 3: fused ELU + mean-pool: atomicAdd Cf[z*HID + col].
// ---------------------------------------------------------------------------
template <int MODE>
__global__ __launch_bounds__(256, 4) void mfma_gemm(
    const short* __restrict__ A, const short* __restrict__ B,
    int K, int lda, int ldb, long sA, long sB,
    float* __restrict__ Cf, short* __restrict__ Ct,
    const float* __restrict__ a_vec, float* __restrict__ Wh1g,
    float* __restrict__ Wh2g) {
  __shared__ short smem[8704];  // As 4096 + Bs 4096; reused as ctile
  short* As = smem;
  short* Bs = smem + 4096;

  const int gx = gridDim.x, gy = gridDim.y;
  int lin = blockIdx.x + gx * (blockIdx.y + gy * blockIdx.z);
  const int per = (gx * gy * gridDim.z) >> 3;
  int work = (lin & 7) * per + (lin >> 3);
  const int bx = work % gx;
  int tmp = work / gx;
  const int by = tmp % gy;
  const int z = tmp / gy;

  A += (long)z * sA;
  B += (long)z * sB;

  const int tid = threadIdx.x;
  const int m0 = by * 128;
  const int n0 = bx * 128;

  const int lane = tid & 63;
  const int wid = tid >> 6;
  const int wm = (wid & 1) * 64;
  const int wn = (wid >> 1) * 64;
  const int l15 = lane & 15;
  const int quad = lane >> 4;
  const int cp = quad ^ ((l15 >> 1) & 3);

  f32x4 acc[4][4];
#pragma unroll
  for (int i = 0; i < 4; ++i)
#pragma unroll
    for (int j = 0; j < 4; ++j) acc[i][j] = (f32x4){0.f, 0.f, 0.f, 0.f};

  for (int k0 = 0; k0 < K; k0 += 32) {
#pragma unroll
    for (int it = 0; it < 2; ++it) {
      int lin2 = it * 256 + tid;
      int r = lin2 >> 2;
      int p = lin2 & 3;
      int kc = p ^ ((r >> 1) & 3);
      cp16(A + (long)(m0 + r) * lda + k0 + kc * 8, &As[lin2 * 8]);
    }
#pragma unroll
    for (int it = 0; it < 2; ++it) {
      int lin2 = it * 256 + tid;
      int r = lin2 >> 2;
      int p = lin2 & 3;
      int kc = p ^ ((r >> 1) & 3);
      cp16(B + (long)(n0 + r) * ldb + k0 + kc * 8, &Bs[lin2 * 8]);
    }
    __syncthreads();

    short8v af[4], bfr[4];
#pragma unroll
    for (int i = 0; i < 4; ++i)
      af[i] = *(const short8v*)(As + (wm + i * 16 + l15) * 32 + cp * 8);
#pragma unroll
    for (int j = 0; j < 4; ++j)
      bfr[j] = *(const short8v*)(Bs + (wn + j * 16 + l15) * 32 + cp * 8);
#pragma unroll
    for (int i = 0; i < 4; ++i)
#pragma unroll
      for (int j = 0; j < 4; ++j)
        acc[i][j] = __builtin_amdgcn_mfma_f32_16x16x32_bf16(af[i], bfr[j],
                                                            acc[i][j], 0, 0, 0);
    __syncthreads();
  }

  // ---- epilogues (C/D layout: col=lane&15 group, row=quad*4+reg) ----
  if constexpr (MODE == 3) {
#pragma unroll
    for (int j = 0; j < 4; ++j) {
      int col = n0 + wn + j * 16 + l15;
      float s = 0.f;
#pragma unroll
      for (int i = 0; i < 4; ++i)
#pragma unroll
        for (int reg = 0; reg < 4; ++reg) {
          float v = acc[i][j][reg];
          s += v > 0.f ? v : (__expf(v) - 1.f);
        }
      s += __shfl_xor(s, 16);
      s += __shfl_xor(s, 32);
      if (quad == 0) atomicAdd(Cf + (long)z * HID + col, s * (1.0f / NN));
    }
  } else {  // MODE 0: a-dot + transposed Ct via LDS [col][row] (stride 136)
    float a1v[4], a2v[4];
#pragma unroll
    for (int j = 0; j < 4; ++j) {
      int colh = n0 + wn + j * 16 + l15;  // single-head output (N=768)
      a1v[j] = a_vec[colh];
      a2v[j] = a_vec[HID + colh];
    }
#pragma unroll
    for (int i = 0; i < 4; ++i) {
      int rb = m0 + wm + i * 16 + quad * 4;
#pragma unroll
      for (int reg = 0; reg < 4; ++reg) {
        float s1 = 0.f, s2 = 0.f;
#pragma unroll
        for (int j = 0; j < 4; ++j) {
          s1 = fmaf(acc[i][j][reg], a1v[j], s1);
          s2 = fmaf(acc[i][j][reg], a2v[j], s2);
        }
#pragma unroll
        for (int off = 1; off < 16; off <<= 1) {
          s1 += __shfl_xor(s1, off);
          s2 += __shfl_xor(s2, off);
        }
        if (l15 == 0) {
          atomicAdd(Wh1g + rb + reg, s1);
          atomicAdd(Wh2g + rb + reg, s2);
        }
      }
    }
    const int bb = m0 >> 11;
    const int ml0 = m0 & 2047;
#pragma unroll
    for (int p = 0; p < 2; ++p) {
      if (wn == p * 64) {
#pragma unroll
        for (int j = 0; j < 4; ++j) {
          int col_l = j * 16 + l15;
#pragma unroll
          for (int i = 0; i < 4; ++i) {
            int row_l = wm + i * 16 + quad * 4;
            short4v pk;
#pragma unroll
            for (int reg = 0; reg < 4; ++reg) pk[reg] = f2bf(acc[i][j][reg]);
            *(short4v*)(smem + col_l * 136 + row_l) = pk;
          }
        }
      }
      __syncthreads();
#pragma unroll
      for (int it = 0; it < 4; ++it) {
        int idx = it * 256 + tid;
        int col_l = idx >> 4;
        int ch = idx & 15;
        short8v ld = *(const short8v*)(smem + col_l * 136 + ch * 8);
        int colh = n0 + p * 64 + col_l;
        *(short8v*)(Ct + ((long)bb * HID + colh) * NN + ml0 + ch * 8) = ld;
      }
      __syncthreads();
    }
  }
}

// ---------------------------------------------------------------------------
// Layer-2 row softmax (materializing, bf16 att). grid 16384. Blocks [0,zn)
// also zero zA (the final output accumulator; write-disjoint from reads).
// ---------------------------------------------------------------------------
__global__ __launch_bounds__(256) void attn_softmax_kernel(
    const float* __restrict__ Wh1, const float* __restrict__ Wh2,
    const unsigned long long* __restrict__ packed, short* __restrict__ att,
    float* __restrict__ zA, int zn) {
  int row = blockIdx.x;
  if (row < zn) zA[row * 256 + threadIdx.x] = 0.f;
  int b = row >> 11;
  const unsigned char* bits = (const unsigned char*)(packed + (long)row * 32);
  const float* wh2b = Wh2 + b * NN;
  const int t = threadIdx.x;
  const int lane = t & 63;
  const int wv = t >> 6;

  unsigned m8 = bits[t];
  float wh1 = Wh1[row];
  float4 wa = ((const float4*)(wh2b + t * 8))[0];
  float4 wb = ((const float4*)(wh2b + t * 8))[1];
  float v[8] = {wa.x, wa.y, wa.z, wa.w, wb.x, wb.y, wb.z, wb.w};

  float lmax = -INFINITY;
#pragma unroll
  for (int k = 0; k < 8; ++k) {
    float s = wh1 + v[k];
    s = s > 0.f ? s : ALPHA * s;
    s = ((m8 >> k) & 1u) ? s : NEGV;
    v[k] = s;
    lmax = fmaxf(lmax, s);
  }

  __shared__ float redm[4], reds[4];
#pragma unroll
  for (int off = 32; off > 0; off >>= 1) lmax = fmaxf(lmax, __shfl_xor(lmax, off));
  if (lane == 0) redm[wv] = lmax;
  __syncthreads();
  float m = fmaxf(fmaxf(redm[0], redm[1]), fmaxf(redm[2], redm[3]));

  float lsum = 0.f;
#pragma unroll
  for (int k = 0; k < 8; ++k) {
    float p = __expf(v[k] - m);
    v[k] = p;
    lsum += p;
  }
#pragma unroll
  for (int off = 32; off > 0; off >>= 1) lsum += __shfl_xor(lsum, off);
  if (lane == 0) reds[wv] = lsum;
  __syncthreads();
  float inv = 1.f / (reds[0] + reds[1] + reds[2] + reds[3]);

  short8v o;
#pragma unroll
  for (int k = 0; k < 8; ++k) o[k] = f2bf(v[k] * inv);
  *(short8v*)(att + (long)row * NN + t * 8) = o;
}

// ---------------------------------------------------------------------------
extern "C" void kernel_launch(void* const* d_in, const int* in_sizes, int n_in,
                              void* d_out, int out_size, void* d_ws,
                              size_t ws_size, hipStream_t stream) {
  const int* node_feats = (const int*)d_in[0];
  const int* adjs = (const int*)d_in[1];
  const float* embed_table = (const float*)d_in[2];
  const float* W_heads = (const float*)d_in[3];
  const float* a_heads = (const float*)d_in[4];
  const float* W_out = (const float*)d_in[5];
  const float* a_out = (const float*)d_in[6];
  float* out = (float*)d_out;

  // workspace layout (~280 MB)
  char* p = (char*)d_ws;
  short* Wt_o = (short*)p;  p += (size_t)HID * (NHEADS * HID) * 2;       // 4.7 MB
  short* Wh_t = (short*)p;  p += (size_t)BB * HID * NN * 2;              // 25 MB
  short* att2 = (short*)p;  p += (size_t)BB * NN * NN * 2;               // 67 MB
  short* hcat = (short*)p;  p += (size_t)MTOT * NHEADS * HID * 2;        // 100 MB
  unsigned long long* padj = (unsigned long long*)p;
  p += (size_t)BB * NN * NN / 8;                                         // 4.2 MB
  float* P16 = (float*)p;   p += (size_t)NHEADS * 16384 * 16 * 4;        // 4 MB
  // contiguous zero region: Wh1 (16384) + Wh2 (16384) + TW (46080)
  float* Wh1 = (float*)p;   p += (size_t)16384 * 4;
  float* Wh2 = (float*)p;   p += (size_t)16384 * 4;
  float* TW = (float*)p;    p += (size_t)VOCAB * NHEADS * HID * 4;
  float* TW1 = (float*)p;   p += (size_t)NHEADS * VOCAB * 4;
  float* TW2 = (float*)p;   p += (size_t)NHEADS * VOCAB * 4;
  if ((size_t)(p - (char*)d_ws) > ws_size) return;

  // 0) setup: W_out transpose; adj pack + zero {Wh1,Wh2,TW}
  transpose_o<<<dim3(96, 24), 256, 0, stream>>>(W_out, Wt_o);
  setup_kernel<<<PACK_B + ZERO_B, 256, 0, stream>>>(adjs, padj, Wh1);

  // 1) layer 1 via 15-row structure: TW, a-dots, bucket softmax, expand
  tw_kernel<<<dim3(12, 4), 256, 0, stream>>>(embed_table, W_heads, TW);
  tw12_kernel<<<NHEADS * VOCAB, 256, 0, stream>>>(TW, a_heads, TW1, TW2);
  bucket_softmax<<<NHEADS * 16384, 256, 0, stream>>>(node_feats, padj, TW1,
                                                     TW2, P16);
  hcat_expand<<<dim3(24, 128), 256, 0, stream>>>(TW, P16, hcat);

  // 2) output GAT layer (full-rank): proj2 -> Wh_t + Wh1/Wh2 atomics
  mfma_gemm<0><<<dim3(HID / 128, MTOT / 128, 1), 256, 0, stream>>>(
      hcat, Wt_o, NHEADS * HID, NHEADS * HID, NHEADS * HID, 0, 0,
      nullptr, Wh_t, a_out, Wh1, Wh2);
  attn_softmax_kernel<<<MTOT, 256, 0, stream>>>(Wh1, Wh2, padj, att2, out, 24);
  mfma_gemm<3><<<dim3(HID / 128, NN / 128, BB), 256, 0, stream>>>(
      att2, Wh_t, NN, NN, NN, (long)NN * NN, (long)HID * NN,
      out, nullptr, nullptr, nullptr, nullptr);
}

// Round 12
// 495.179 us; speedup vs baseline: 2.1071x; 1.3780x over previous
//
#include <hip/hip_runtime.h>
#include <math.h>

#define BB 8
#define NN 2048
#define HID 768
#define NHEADS 4
#define VOCAB 15
#define ALPHA 0.2f
#define NEGV -9e15f
#define MTOT (BB * NN)  // 16384

using short4v = __attribute__((ext_vector_type(4))) short;
using short8v = __attribute__((ext_vector_type(8))) short;
using f32x4 = __attribute__((ext_vector_type(4))) float;

__device__ __forceinline__ short f2bf(float f) {
  union { float f; unsigned u; } x;
  x.f = f;
  unsigned r = x.u + 0x7fffu + ((x.u >> 16) & 1u);
  return (short)(r >> 16);
}

__device__ __forceinline__ void cp16(const void* g, void* l) {
  __builtin_amdgcn_global_load_lds(
      (const __attribute__((address_space(1))) unsigned int*)g,
      (__attribute__((address_space(3))) unsigned int*)l, 16, 0, 0);
}

// ---------------------------------------------------------------------------
// W_out transpose -> bf16 [n][k] (3072x768 -> 768x3072)
// ---------------------------------------------------------------------------
__global__ __launch_bounds__(256) void transpose_o(
    const float* __restrict__ W, short* __restrict__ Wt) {
  __shared__ float t[32][33];
  const int K = NHEADS * HID, N = HID;
  int k0 = blockIdx.x * 32, n0 = blockIdx.y * 32;
  int tx = threadIdx.x & 31, ty = threadIdx.x >> 5;
#pragma unroll
  for (int i = 0; i < 32; i += 8) t[ty + i][tx] = W[(long)(k0 + ty + i) * N + n0 + tx];
  __syncthreads();
#pragma unroll
  for (int i = 0; i < 32; i += 8)
    Wt[(long)(n0 + ty + i) * K + k0 + tx] = f2bf(t[tx][ty + i]);
}

// ---------------------------------------------------------------------------
// Fused setup: [0,131072) adjacency bit-pack; [+308) zero {Wh1,Wh2,TW};
// [+64) per-batch vocab bitmasks nfm[b][v][word] via ballot.
// ---------------------------------------------------------------------------
#define PACK_B 131072
#define ZERO_B 308
#define NFM_B 64
__global__ __launch_bounds__(256) void setup_kernel(
    const int* __restrict__ adj, unsigned long long* __restrict__ packed,
    float* __restrict__ zbase, const int* __restrict__ nf,
    unsigned long long* __restrict__ nfm) {
  const int bid = blockIdx.x;
  const int tid = threadIdx.x;
  if (bid < PACK_B) {
    long idx = (long)bid * 256 + tid;
    unsigned long long m = __ballot(adj[idx] > 0);
    if ((tid & 63) == 0) packed[idx >> 6] = m;
  } else if (bid < PACK_B + ZERO_B) {
    zbase[(bid - PACK_B) * 256 + tid] = 0.f;
  } else {
    // nfmask: block c of batch b handles j in [c*256, c*256+256)
    int r = bid - PACK_B - ZERO_B;  // 0..63
    int b = r >> 3, c = r & 7;
    int w = tid >> 6;  // wave 0..3
    int j = c * 256 + tid;
    int nfv = nf[b * NN + j];
#pragma unroll
    for (int v = 0; v < VOCAB; ++v) {
      unsigned long long m = __ballot(nfv == v);
      if ((tid & 63) == 0) nfm[((long)b * VOCAB + v) * 32 + c * 4 + w] = m;
    }
  }
}

// ---------------------------------------------------------------------------
// TW[v][c] = sum_k table[v][k] * W_heads[h(c)][k][n(c)]  (fp32, 15 x 3072)
// ---------------------------------------------------------------------------
__global__ __launch_bounds__(256) void tw_kernel(
    const float* __restrict__ table, const float* __restrict__ W_heads,
    float* __restrict__ TW) {
  __shared__ float tbl[VOCAB][192];
  const int c = blockIdx.x * 256 + threadIdx.x;  // 0..3071
  const int h = (blockIdx.x * 256) / HID;        // uniform per block
  const int n = c - h * HID;
  const int k0 = blockIdx.y * 192;
  for (int idx = threadIdx.x; idx < VOCAB * 192; idx += 256)
    tbl[idx / 192][idx % 192] = table[(idx / 192) * HID + k0 + idx % 192];
  __syncthreads();
  float acc[VOCAB];
#pragma unroll
  for (int v = 0; v < VOCAB; ++v) acc[v] = 0.f;
  for (int kk = 0; kk < 192; ++kk) {
    float w = W_heads[(long)h * HID * HID + (long)(k0 + kk) * HID + n];
#pragma unroll
    for (int v = 0; v < VOCAB; ++v) acc[v] = fmaf(tbl[v][kk], w, acc[v]);
  }
#pragma unroll
  for (int v = 0; v < VOCAB; ++v) atomicAdd(&TW[v * (NHEADS * HID) + c], acc[v]);
}

// ---------------------------------------------------------------------------
// TW1[h][v] = TW[v][h*HID:] . a1_h ; TW2 likewise. grid 60 blocks.
// ---------------------------------------------------------------------------
__global__ __launch_bounds__(256) void tw12_kernel(
    const float* __restrict__ TW, const float* __restrict__ a_heads,
    float* __restrict__ TW1, float* __restrict__ TW2) {
  int h = blockIdx.x / VOCAB, v = blockIdx.x % VOCAB;
  const float* twr = TW + v * (NHEADS * HID) + h * HID;
  const float* a1 = a_heads + h * 2 * HID;
  float s1 = 0.f, s2 = 0.f;
  for (int n = threadIdx.x; n < HID; n += 256) {
    float t = twr[n];
    s1 = fmaf(t, a1[n], s1);
    s2 = fmaf(t, a1[HID + n], s2);
  }
  __shared__ float r1[256], r2[256];
  r1[threadIdx.x] = s1;
  r2[threadIdx.x] = s2;
  __syncthreads();
  for (int s = 128; s > 0; s >>= 1) {
    if (threadIdx.x < s) {
      r1[threadIdx.x] += r1[threadIdx.x + s];
      r2[threadIdx.x] += r2[threadIdx.x + s];
    }
    __syncthreads();
  }
  if (threadIdx.x == 0) {
    TW1[h * VOCAB + v] = r1[0];
    TW2[h * VOCAB + v] = r2[0];
  }
}

// ---------------------------------------------------------------------------
// P16 via popcount: one wave per row. cnt[v] = popcount(padj_row & nfm[b][v]);
// then 15-value softmax for all 4 heads in parallel (lane = h*16 + v).
// P16[h][rowm][v] = cnt_v * exp(lrelu(TW1[h][nf_i]+TW2[h][v]) - m) / sum.
// All-masked row fallback: uniform att -> P ~ popcount(nfm) weights.
// ---------------------------------------------------------------------------
__global__ __launch_bounds__(256) void p16_kernel(
    const int* __restrict__ nf, const unsigned* __restrict__ padj32,
    const unsigned* __restrict__ nfm32, const float* __restrict__ TW1,
    const float* __restrict__ TW2, float* __restrict__ P16) {
  const int t = threadIdx.x;
  const int wv = t >> 6;
  const int lane = t & 63;
  const int rowm = blockIdx.x * 4 + wv;
  const int b = rowm >> 11;
  __shared__ float cnts[4][16];

  unsigned a = padj32[(long)rowm * 64 + lane];
  const unsigned* nb = nfm32 + (long)b * VOCAB * 64 + lane;
  int cnt[VOCAB];
#pragma unroll
  for (int v = 0; v < VOCAB; ++v) cnt[v] = __popc(a & nb[v * 64]);
#pragma unroll
  for (int off = 1; off < 64; off <<= 1)
#pragma unroll
    for (int v = 0; v < VOCAB; ++v) cnt[v] += __shfl_xor(cnt[v], off);
  int cntsum = 0;
#pragma unroll
  for (int v = 0; v < VOCAB; ++v) cntsum += cnt[v];
  const bool use_full = (cntsum == 0);  // wave-uniform
  if (use_full) {
#pragma unroll
    for (int v = 0; v < VOCAB; ++v) cnt[v] = __popc(nb[v * 64]);
#pragma unroll
    for (int off = 1; off < 64; off <<= 1)
#pragma unroll
      for (int v = 0; v < VOCAB; ++v) cnt[v] += __shfl_xor(cnt[v], off);
  }
  if (lane < 16) cnts[wv][lane] = (lane < VOCAB) ? (float)cnt[lane] : 0.f;
  __syncthreads();

  const int h = lane >> 4;
  const int v = lane & 15;
  const int nfi = nf[b * NN + (rowm & 2047)];
  float cvf = cnts[wv][v];
  bool valid = (v < VOCAB) && (cvf > 0.f);
  float logit = 0.f;
  if (!use_full) {
    float s = TW1[h * VOCAB + nfi] + ((v < VOCAB) ? TW2[h * VOCAB + v] : 0.f);
    logit = s > 0.f ? s : ALPHA * s;
  }
  float mv = valid ? logit : -INFINITY;
#pragma unroll
  for (int off = 1; off < 16; off <<= 1) mv = fmaxf(mv, __shfl_xor(mv, off));
  float pv = valid ? cvf * __expf(logit - mv) : 0.f;
  float sum = pv;
#pragma unroll
  for (int off = 1; off < 16; off <<= 1) sum += __shfl_xor(sum, off);
  if (v < VOCAB) P16[((long)h * 16384 + rowm) * 16 + v] = pv / sum;
}

// ---------------------------------------------------------------------------
// hcat[r][h*HID+colh] = ELU( sum_v P16[h][r][v] * TW[v][h*HID+colh] ) -> bf16
// ---------------------------------------------------------------------------
__global__ __launch_bounds__(256) void hcat_expand(
    const float* __restrict__ TW, const float* __restrict__ P16,
    short* __restrict__ hcat) {
  __shared__ float twl[VOCAB * 128];
  __shared__ float pl[128 * 16];
  const int c0 = blockIdx.x * 128;
  const int r0 = blockIdx.y * 128;
  const int h = c0 / HID;
  const int t = threadIdx.x;
  for (int idx = t; idx < VOCAB * 128; idx += 256)
    twl[idx] = TW[(idx / 128) * (NHEADS * HID) + c0 + (idx & 127)];
  for (int idx = t; idx < 128 * 16; idx += 256)
    pl[idx] = P16[((long)h * 16384 + r0 + (idx >> 4)) * 16 + (idx & 15)];
  __syncthreads();
  const int clb = (t & 31) * 4;
  const int rlb = (t >> 5) * 16;
#pragma unroll 4
  for (int rr = 0; rr < 16; ++rr) {
    int rl = rlb + rr;
    short4v o;
#pragma unroll
    for (int cc = 0; cc < 4; ++cc) {
      float s = 0.f;
#pragma unroll
      for (int vv = 0; vv < VOCAB; ++vv)
        s = fmaf(pl[rl * 16 + vv], twl[vv * 128 + clb + cc], s);
      s = s > 0.f ? s : (__expf(s) - 1.f);
      o[cc] = f2bf(s);
    }
    *(short4v*)(hcat + (long)(r0 + rl) * (NHEADS * HID) + c0 + clb) = o;
  }
}

// ---------------------------------------------------------------------------
// bf16 MFMA GEMM, 128x128 tile, BK=32, XCD swizzle, LDS-repacked epilogues.
// MODE 0: Ct bf16 [bb][colh][row] via LDS + fused a-dot atomics (layer 2).
// MODE 3: fused ELU + mean-pool: atomicAdd Cf[z*HID + col].
// ---------------------------------------------------------------------------
template <int MODE>
__global__ __launch_bounds__(256, 4) void mfma_gemm(
    const short* __restrict__ A, const short* __restrict__ B,
    int K, int lda, int ldb, long sA, long sB,
    float* __restrict__ Cf, short* __restrict__ Ct,
    const float* __restrict__ a_vec, float* __restrict__ Wh1g,
    float* __restrict__ Wh2g) {
  __shared__ short smem[8704];  // As 4096 + Bs 4096; reused as ctile
  short* As = smem;
  short* Bs = smem + 4096;

  const int gx = gridDim.x, gy = gridDim.y;
  int lin = blockIdx.x + gx * (blockIdx.y + gy * blockIdx.z);
  const int per = (gx * gy * gridDim.z) >> 3;
  int work = (lin & 7) * per + (lin >> 3);
  const int bx = work % gx;
  int tmp = work / gx;
  const int by = tmp % gy;
  const int z = tmp / gy;

  A += (long)z * sA;
  B += (long)z * sB;

  const int tid = threadIdx.x;
  const int m0 = by * 128;
  const int n0 = bx * 128;

  const int lane = tid & 63;
  const int wid = tid >> 6;
  const int wm = (wid & 1) * 64;
  const int wn = (wid >> 1) * 64;
  const int l15 = lane & 15;
  const int quad = lane >> 4;
  const int cp = quad ^ ((l15 >> 1) & 3);

  f32x4 acc[4][4];
#pragma unroll
  for (int i = 0; i < 4; ++i)
#pragma unroll
    for (int j = 0; j < 4; ++j) acc[i][j] = (f32x4){0.f, 0.f, 0.f, 0.f};

  for (int k0 = 0; k0 < K; k0 += 32) {
#pragma unroll
    for (int it = 0; it < 2; ++it) {
      int lin2 = it * 256 + tid;
      int r = lin2 >> 2;
      int p = lin2 & 3;
      int kc = p ^ ((r >> 1) & 3);
      cp16(A + (long)(m0 + r) * lda + k0 + kc * 8, &As[lin2 * 8]);
    }
#pragma unroll
    for (int it = 0; it < 2; ++it) {
      int lin2 = it * 256 + tid;
      int r = lin2 >> 2;
      int p = lin2 & 3;
      int kc = p ^ ((r >> 1) & 3);
      cp16(B + (long)(n0 + r) * ldb + k0 + kc * 8, &Bs[lin2 * 8]);
    }
    __syncthreads();

    short8v af[4], bfr[4];
#pragma unroll
    for (int i = 0; i < 4; ++i)
      af[i] = *(const short8v*)(As + (wm + i * 16 + l15) * 32 + cp * 8);
#pragma unroll
    for (int j = 0; j < 4; ++j)
      bfr[j] = *(const short8v*)(Bs + (wn + j * 16 + l15) * 32 + cp * 8);
#pragma unroll
    for (int i = 0; i < 4; ++i)
#pragma unroll
      for (int j = 0; j < 4; ++j)
        acc[i][j] = __builtin_amdgcn_mfma_f32_16x16x32_bf16(af[i], bfr[j],
                                                            acc[i][j], 0, 0, 0);
    __syncthreads();
  }

  // ---- epilogues (C/D layout: col=lane&15 group, row=quad*4+reg) ----
  if constexpr (MODE == 3) {
#pragma unroll
    for (int j = 0; j < 4; ++j) {
      int col = n0 + wn + j * 16 + l15;
      float s = 0.f;
#pragma unroll
      for (int i = 0; i < 4; ++i)
#pragma unroll
        for (int reg = 0; reg < 4; ++reg) {
          float v = acc[i][j][reg];
          s += v > 0.f ? v : (__expf(v) - 1.f);
        }
      s += __shfl_xor(s, 16);
      s += __shfl_xor(s, 32);
      if (quad == 0) atomicAdd(Cf + (long)z * HID + col, s * (1.0f / NN));
    }
  } else {  // MODE 0: a-dot + transposed Ct via LDS [col][row] (stride 136)
    float a1v[4], a2v[4];
#pragma unroll
    for (int j = 0; j < 4; ++j) {
      int colh = n0 + wn + j * 16 + l15;  // single-head output (N=768)
      a1v[j] = a_vec[colh];
      a2v[j] = a_vec[HID + colh];
    }
#pragma unroll
    for (int i = 0; i < 4; ++i) {
      int rb = m0 + wm + i * 16 + quad * 4;
#pragma unroll
      for (int reg = 0; reg < 4; ++reg) {
        float s1 = 0.f, s2 = 0.f;
#pragma unroll
        for (int j = 0; j < 4; ++j) {
          s1 = fmaf(acc[i][j][reg], a1v[j], s1);
          s2 = fmaf(acc[i][j][reg], a2v[j], s2);
        }
#pragma unroll
        for (int off = 1; off < 16; off <<= 1) {
          s1 += __shfl_xor(s1, off);
          s2 += __shfl_xor(s2, off);
        }
        if (l15 == 0) {
          atomicAdd(Wh1g + rb + reg, s1);
          atomicAdd(Wh2g + rb + reg, s2);
        }
      }
    }
    const int bb = m0 >> 11;
    const int ml0 = m0 & 2047;
#pragma unroll
    for (int p = 0; p < 2; ++p) {
      if (wn == p * 64) {
#pragma unroll
        for (int j = 0; j < 4; ++j) {
          int col_l = j * 16 + l15;
#pragma unroll
          for (int i = 0; i < 4; ++i) {
            int row_l = wm + i * 16 + quad * 4;
            short4v pk;
#pragma unroll
            for (int reg = 0; reg < 4; ++reg) pk[reg] = f2bf(acc[i][j][reg]);
            *(short4v*)(smem + col_l * 136 + row_l) = pk;
          }
        }
      }
      __syncthreads();
#pragma unroll
      for (int it = 0; it < 4; ++it) {
        int idx = it * 256 + tid;
        int col_l = idx >> 4;
        int ch = idx & 15;
        short8v ld = *(const short8v*)(smem + col_l * 136 + ch * 8);
        int colh = n0 + p * 64 + col_l;
        *(short8v*)(Ct + ((long)bb * HID + colh) * NN + ml0 + ch * 8) = ld;
      }
      __syncthreads();
    }
  }
}

// ---------------------------------------------------------------------------
// Layer-2 row softmax (materializing, bf16 att). grid 16384. Blocks [0,zn)
// also zero zA (final output accumulator; write-disjoint from reads).
// ---------------------------------------------------------------------------
__global__ __launch_bounds__(256) void attn_softmax_kernel(
    const float* __restrict__ Wh1, const float* __restrict__ Wh2,
    const unsigned long long* __restrict__ packed, short* __restrict__ att,
    float* __restrict__ zA, int zn) {
  int row = blockIdx.x;
  if (row < zn) zA[row * 256 + threadIdx.x] = 0.f;
  int b = row >> 11;
  const unsigned char* bits = (const unsigned char*)(packed + (long)row * 32);
  const float* wh2b = Wh2 + b * NN;
  const int t = threadIdx.x;
  const int lane = t & 63;
  const int wv = t >> 6;

  unsigned m8 = bits[t];
  float wh1 = Wh1[row];
  float4 wa = ((const float4*)(wh2b + t * 8))[0];
  float4 wb = ((const float4*)(wh2b + t * 8))[1];
  float v[8] = {wa.x, wa.y, wa.z, wa.w, wb.x, wb.y, wb.z, wb.w};

  float lmax = -INFINITY;
#pragma unroll
  for (int k = 0; k < 8; ++k) {
    float s = wh1 + v[k];
    s = s > 0.f ? s : ALPHA * s;
    s = ((m8 >> k) & 1u) ? s : NEGV;
    v[k] = s;
    lmax = fmaxf(lmax, s);
  }

  __shared__ float redm[4], reds[4];
#pragma unroll
  for (int off = 32; off > 0; off >>= 1) lmax = fmaxf(lmax, __shfl_xor(lmax, off));
  if (lane == 0) redm[wv] = lmax;
  __syncthreads();
  float m = fmaxf(fmaxf(redm[0], redm[1]), fmaxf(redm[2], redm[3]));

  float lsum = 0.f;
#pragma unroll
  for (int k = 0; k < 8; ++k) {
    float p = __expf(v[k] - m);
    v[k] = p;
    lsum += p;
  }
#pragma unroll
  for (int off = 32; off > 0; off >>= 1) lsum += __shfl_xor(lsum, off);
  if (lane == 0) reds[wv] = lsum;
  __syncthreads();
  float inv = 1.f / (reds[0] + reds[1] + reds[2] + reds[3]);

  short8v o;
#pragma unroll
  for (int k = 0; k < 8; ++k) o[k] = f2bf(v[k] * inv);
  *(short8v*)(att + (long)row * NN + t * 8) = o;
}

// ---------------------------------------------------------------------------
extern "C" void kernel_launch(void* const* d_in, const int* in_sizes, int n_in,
                              void* d_out, int out_size, void* d_ws,
                              size_t ws_size, hipStream_t stream) {
  const int* node_feats = (const int*)d_in[0];
  const int* adjs = (const int*)d_in[1];
  const float* embed_table = (const float*)d_in[2];
  const float* W_heads = (const float*)d_in[3];
  const float* a_heads = (const float*)d_in[4];
  const float* W_out = (const float*)d_in[5];
  const float* a_out = (const float*)d_in[6];
  float* out = (float*)d_out;

  // workspace layout (~210 MB)
  char* p = (char*)d_ws;
  short* Wt_o = (short*)p;  p += (size_t)HID * (NHEADS * HID) * 2;       // 4.7 MB
  short* Wh_t = (short*)p;  p += (size_t)BB * HID * NN * 2;              // 25 MB
  short* att2 = (short*)p;  p += (size_t)BB * NN * NN * 2;               // 67 MB
  short* hcat = (short*)p;  p += (size_t)MTOT * NHEADS * HID * 2;        // 100 MB
  unsigned long long* padj = (unsigned long long*)p;
  p += (size_t)BB * NN * NN / 8;                                         // 4.2 MB
  float* P16 = (float*)p;   p += (size_t)NHEADS * 16384 * 16 * 4;        // 4 MB
  // contiguous zero region: Wh1 (16384) + Wh2 (16384) + TW (46080)
  float* Wh1 = (float*)p;   p += (size_t)16384 * 4;
  float* Wh2 = (float*)p;   p += (size_t)16384 * 4;
  float* TW = (float*)p;    p += (size_t)VOCAB * NHEADS * HID * 4;
  float* TW1 = (float*)p;   p += (size_t)NHEADS * VOCAB * 4;
  float* TW2 = (float*)p;   p += (size_t)NHEADS * VOCAB * 4;
  unsigned long long* nfm = (unsigned long long*)p;
  p += (size_t)BB * VOCAB * 32 * 8;                                      // 30 KB
  if ((size_t)(p - (char*)d_ws) > ws_size) return;

  // 0) setup: W_out transpose; adj pack + zero {Wh1,Wh2,TW} + vocab masks
  transpose_o<<<dim3(96, 24), 256, 0, stream>>>(W_out, Wt_o);
  setup_kernel<<<PACK_B + ZERO_B + NFM_B, 256, 0, stream>>>(
      adjs, padj, Wh1, node_feats, nfm);

  // 1) layer 1 via rank-15 structure: TW, a-dots, popcount-P16, expand
  tw_kernel<<<dim3(12, 4), 256, 0, stream>>>(embed_table, W_heads, TW);
  tw12_kernel<<<NHEADS * VOCAB, 256, 0, stream>>>(TW, a_heads, TW1, TW2);
  p16_kernel<<<16384 / 4, 256, 0, stream>>>(
      node_feats, (const unsigned*)padj, (const unsigned*)nfm, TW1, TW2, P16);
  hcat_expand<<<dim3(24, 128), 256, 0, stream>>>(TW, P16, hcat);

  // 2) output GAT layer (full-rank): proj2 -> Wh_t + Wh1/Wh2 atomics
  mfma_gemm<0><<<dim3(HID / 128, MTOT / 128, 1), 256, 0, stream>>>(
      hcat, Wt_o, NHEADS * HID, NHEADS * HID, NHEADS * HID, 0, 0,
      nullptr, Wh_t, a_out, Wh1, Wh2);
  attn_softmax_kernel<<<MTOT, 256, 0, stream>>>(Wh1, Wh2, padj, att2, out, 24);
  mfma_gemm<3><<<dim3(HID / 128, NN / 128, BB), 256, 0, stream>>>(
      att2, Wh_t, NN, NN, NN, (long)NN * NN, (long)HID * NN,
      out, nullptr, nullptr, nullptr, nullptr);
}

// Round 13
// 462.761 us; speedup vs baseline: 2.2547x; 1.0701x over previous
//
#include <hip/hip_runtime.h>
#include <math.h>

#define BB 8
#define NN 2048
#define HID 768
#define NHEADS 4
#define VOCAB 15
#define ALPHA 0.2f
#define NEGV -9e15f
#define MTOT (BB * NN)  // 16384

using short4v = __attribute__((ext_vector_type(4))) short;
using short8v = __attribute__((ext_vector_type(8))) short;
using f32x4 = __attribute__((ext_vector_type(4))) float;

__device__ __forceinline__ short f2bf(float f) {
  union { float f; unsigned u; } x;
  x.f = f;
  unsigned r = x.u + 0x7fffu + ((x.u >> 16) & 1u);
  return (short)(r >> 16);
}

__device__ __forceinline__ void cp16(const void* g, void* l) {
  __builtin_amdgcn_global_load_lds(
      (const __attribute__((address_space(1))) unsigned int*)g,
      (__attribute__((address_space(3))) unsigned int*)l, 16, 0, 0);
}

// ---------------------------------------------------------------------------
// Mega-setup: [0,PACK_B) adjacency bit-pack; [+ZERO_B) zero {Wh1,Wh2,TW};
// [+NFM_B) per-batch vocab bitmasks; [+TRAN_B) W_out transpose -> bf16 [n][k].
// ---------------------------------------------------------------------------
#define PACK_B 131072
#define ZERO_B 308
#define NFM_B 64
#define TRAN_B 2304  // 96 x 24 tiles of 32x32
__global__ __launch_bounds__(256) void setup_kernel(
    const int* __restrict__ adj, unsigned long long* __restrict__ packed,
    float* __restrict__ zbase, const int* __restrict__ nf,
    unsigned long long* __restrict__ nfm, const float* __restrict__ W_out,
    short* __restrict__ Wt_o) {
  const int bid = blockIdx.x;
  const int tid = threadIdx.x;
  if (bid < PACK_B) {
    long idx = (long)bid * 256 + tid;
    unsigned long long m = __ballot(adj[idx] > 0);
    if ((tid & 63) == 0) packed[idx >> 6] = m;
  } else if (bid < PACK_B + ZERO_B) {
    zbase[(bid - PACK_B) * 256 + tid] = 0.f;
  } else if (bid < PACK_B + ZERO_B + NFM_B) {
    // vocab bitmasks: block c of batch b handles j in [c*256, c*256+256)
    int r = bid - PACK_B - ZERO_B;  // 0..63
    int b = r >> 3, c = r & 7;
    int w = tid >> 6;  // wave 0..3
    int j = c * 256 + tid;
    int nfv = nf[b * NN + j];
#pragma unroll
    for (int v = 0; v < VOCAB; ++v) {
      unsigned long long m = __ballot(nfv == v);
      if ((tid & 63) == 0) nfm[((long)b * VOCAB + v) * 32 + c * 4 + w] = m;
    }
  } else {
    // W_out transpose (3072x768 -> bf16 768x3072)
    __shared__ float t[32][33];
    int r2 = bid - PACK_B - ZERO_B - NFM_B;
    const int K = NHEADS * HID, N = HID;
    int k0 = (r2 % 96) * 32, n0 = (r2 / 96) * 32;
    int tx = tid & 31, ty = tid >> 5;
#pragma unroll
    for (int i = 0; i < 32; i += 8)
      t[ty + i][tx] = W_out[(long)(k0 + ty + i) * N + n0 + tx];
    __syncthreads();
#pragma unroll
    for (int i = 0; i < 32; i += 8)
      Wt_o[(long)(n0 + ty + i) * K + k0 + tx] = f2bf(t[tx][ty + i]);
  }
}

// ---------------------------------------------------------------------------
// TW[v][c] = sum_k table[v][k] * W_heads[h(c)][k][n(c)]  (fp32, 15 x 3072)
// grid (12, 16): x -> 256-col chunk (within one head), y -> k-chunk of 48.
// Unroll-8 lets the compiler pipeline the W loads (latency hiding).
// ---------------------------------------------------------------------------
__global__ __launch_bounds__(256) void tw_kernel(
    const float* __restrict__ table, const float* __restrict__ W_heads,
    float* __restrict__ TW) {
  __shared__ float tbl[VOCAB][48];
  const int c = blockIdx.x * 256 + threadIdx.x;  // 0..3071
  const int h = (blockIdx.x * 256) / HID;        // uniform per block
  const int n = c - h * HID;
  const int k0 = blockIdx.y * 48;
  for (int idx = threadIdx.x; idx < VOCAB * 48; idx += 256)
    tbl[idx / 48][idx % 48] = table[(idx / 48) * HID + k0 + idx % 48];
  __syncthreads();
  float acc[VOCAB];
#pragma unroll
  for (int v = 0; v < VOCAB; ++v) acc[v] = 0.f;
  const float* wp = W_heads + (long)h * HID * HID + (long)k0 * HID + n;
#pragma unroll 8
  for (int kk = 0; kk < 48; ++kk) {
    float w = wp[(long)kk * HID];
#pragma unroll
    for (int v = 0; v < VOCAB; ++v) acc[v] = fmaf(tbl[v][kk], w, acc[v]);
  }
#pragma unroll
  for (int v = 0; v < VOCAB; ++v) atomicAdd(&TW[v * (NHEADS * HID) + c], acc[v]);
}

// ---------------------------------------------------------------------------
// TW1[h][v] = TW[v][h*HID:] . a1_h ; TW2 likewise. grid 60 blocks.
// ---------------------------------------------------------------------------
__global__ __launch_bounds__(256) void tw12_kernel(
    const float* __restrict__ TW, const float* __restrict__ a_heads,
    float* __restrict__ TW1, float* __restrict__ TW2) {
  int h = blockIdx.x / VOCAB, v = blockIdx.x % VOCAB;
  const float* twr = TW + v * (NHEADS * HID) + h * HID;
  const float* a1 = a_heads + h * 2 * HID;
  float s1 = 0.f, s2 = 0.f;
  for (int n = threadIdx.x; n < HID; n += 256) {
    float t = twr[n];
    s1 = fmaf(t, a1[n], s1);
    s2 = fmaf(t, a1[HID + n], s2);
  }
  __shared__ float r1[256], r2[256];
  r1[threadIdx.x] = s1;
  r2[threadIdx.x] = s2;
  __syncthreads();
  for (int s = 128; s > 0; s >>= 1) {
    if (threadIdx.x < s) {
      r1[threadIdx.x] += r1[threadIdx.x + s];
      r2[threadIdx.x] += r2[threadIdx.x + s];
    }
    __syncthreads();
  }
  if (threadIdx.x == 0) {
    TW1[h * VOCAB + v] = r1[0];
    TW2[h * VOCAB + v] = r2[0];
  }
}

// ---------------------------------------------------------------------------
// P16 via popcount: one wave per row. cnt[v] = popcount(padj_row & nfm[b][v]);
// then 15-value softmax for all 4 heads in parallel (lane = h*16 + v).
// All-masked row fallback: uniform att -> P ~ popcount(nfm) weights.
// ---------------------------------------------------------------------------
__global__ __launch_bounds__(256) void p16_kernel(
    const int* __restrict__ nf, const unsigned* __restrict__ padj32,
    const unsigned* __restrict__ nfm32, const float* __restrict__ TW1,
    const float* __restrict__ TW2, float* __restrict__ P16) {
  const int t = threadIdx.x;
  const int wv = t >> 6;
  const int lane = t & 63;
  const int rowm = blockIdx.x * 4 + wv;
  const int b = rowm >> 11;
  __shared__ float cnts[4][16];

  unsigned a = padj32[(long)rowm * 64 + lane];
  const unsigned* nb = nfm32 + (long)b * VOCAB * 64 + lane;
  int cnt[VOCAB];
#pragma unroll
  for (int v = 0; v < VOCAB; ++v) cnt[v] = __popc(a & nb[v * 64]);
#pragma unroll
  for (int off = 1; off < 64; off <<= 1)
#pragma unroll
    for (int v = 0; v < VOCAB; ++v) cnt[v] += __shfl_xor(cnt[v], off);
  int cntsum = 0;
#pragma unroll
  for (int v = 0; v < VOCAB; ++v) cntsum += cnt[v];
  const bool use_full = (cntsum == 0);  // wave-uniform
  if (use_full) {
#pragma unroll
    for (int v = 0; v < VOCAB; ++v) cnt[v] = __popc(nb[v * 64]);
#pragma unroll
    for (int off = 1; off < 64; off <<= 1)
#pragma unroll
      for (int v = 0; v < VOCAB; ++v) cnt[v] += __shfl_xor(cnt[v], off);
  }
  if (lane < 16) cnts[wv][lane] = (lane < VOCAB) ? (float)cnt[lane] : 0.f;
  __syncthreads();

  const int h = lane >> 4;
  const int v = lane & 15;
  const int nfi = nf[b * NN + (rowm & 2047)];
  float cvf = cnts[wv][v];
  bool valid = (v < VOCAB) && (cvf > 0.f);
  float logit = 0.f;
  if (!use_full) {
    float s = TW1[h * VOCAB + nfi] + ((v < VOCAB) ? TW2[h * VOCAB + v] : 0.f);
    logit = s > 0.f ? s : ALPHA * s;
  }
  float mv = valid ? logit : -INFINITY;
#pragma unroll
  for (int off = 1; off < 16; off <<= 1) mv = fmaxf(mv, __shfl_xor(mv, off));
  float pv = valid ? cvf * __expf(logit - mv) : 0.f;
  float sum = pv;
#pragma unroll
  for (int off = 1; off < 16; off <<= 1) sum += __shfl_xor(sum, off);
  if (v < VOCAB) P16[((long)h * 16384 + rowm) * 16 + v] = pv / sum;
}

// ---------------------------------------------------------------------------
// hcat[r][h*HID+colh] = ELU( sum_v P16[h][r][v] * TW[v][h*HID+colh] ) -> bf16
// ---------------------------------------------------------------------------
__global__ __launch_bounds__(256) void hcat_expand(
    const float* __restrict__ TW, const float* __restrict__ P16,
    short* __restrict__ hcat) {
  __shared__ float twl[VOCAB * 128];
  __shared__ float pl[128 * 16];
  const int c0 = blockIdx.x * 128;
  const int r0 = blockIdx.y * 128;
  const int h = c0 / HID;
  const int t = threadIdx.x;
  for (int idx = t; idx < VOCAB * 128; idx += 256)
    twl[idx] = TW[(idx / 128) * (NHEADS * HID) + c0 + (idx & 127)];
  for (int idx = t; idx < 128 * 16; idx += 256)
    pl[idx] = P16[((long)h * 16384 + r0 + (idx >> 4)) * 16 + (idx & 15)];
  __syncthreads();
  const int clb = (t & 31) * 4;
  const int rlb = (t >> 5) * 16;
#pragma unroll 4
  for (int rr = 0; rr < 16; ++rr) {
    int rl = rlb + rr;
    short4v o;
#pragma unroll
    for (int cc = 0; cc < 4; ++cc) {
      float s = 0.f;
#pragma unroll
      for (int vv = 0; vv < VOCAB; ++vv)
        s = fmaf(pl[rl * 16 + vv], twl[vv * 128 + clb + cc], s);
      s = s > 0.f ? s : (__expf(s) - 1.f);
      o[cc] = f2bf(s);
    }
    *(short4v*)(hcat + (long)(r0 + rl) * (NHEADS * HID) + c0 + clb) = o;
  }
}

// ---------------------------------------------------------------------------
// bf16 MFMA GEMM, 128x128 tile, BK=32, XCD swizzle, LDS-repacked epilogues.
// MODE 0: Ct bf16 [bb][colh][row] via LDS + fused a-dot atomics (layer 2).
// MODE 3: fused ELU + mean-pool: atomicAdd Cf[z*HID + col].
// ---------------------------------------------------------------------------
template <int MODE>
__global__ __launch_bounds__(256, 4) void mfma_gemm(
    const short* __restrict__ A, const short* __restrict__ B,
    int K, int lda, int ldb, long sA, long sB,
    float* __restrict__ Cf, short* __restrict__ Ct,
    const float* __restrict__ a_vec, float* __restrict__ Wh1g,
    float* __restrict__ Wh2g) {
  __shared__ short smem[8704];  // As 4096 + Bs 4096; reused as ctile
  short* As = smem;
  short* Bs = smem + 4096;

  const int gx = gridDim.x, gy = gridDim.y;
  int lin = blockIdx.x + gx * (blockIdx.y + gy * blockIdx.z);
  const int per = (gx * gy * gridDim.z) >> 3;
  int work = (lin & 7) * per + (lin >> 3);
  const int bx = work % gx;
  int tmp = work / gx;
  const int by = tmp % gy;
  const int z = tmp / gy;

  A += (long)z * sA;
  B += (long)z * sB;

  const int tid = threadIdx.x;
  const int m0 = by * 128;
  const int n0 = bx * 128;

  const int lane = tid & 63;
  const int wid = tid >> 6;
  const int wm = (wid & 1) * 64;
  const int wn = (wid >> 1) * 64;
  const int l15 = lane & 15;
  const int quad = lane >> 4;
  const int cp = quad ^ ((l15 >> 1) & 3);

  f32x4 acc[4][4];
#pragma unroll
  for (int i = 0; i < 4; ++i)
#pragma unroll
    for (int j = 0; j < 4; ++j) acc[i][j] = (f32x4){0.f, 0.f, 0.f, 0.f};

  for (int k0 = 0; k0 < K; k0 += 32) {
#pragma unroll
    for (int it = 0; it < 2; ++it) {
      int lin2 = it * 256 + tid;
      int r = lin2 >> 2;
      int p = lin2 & 3;
      int kc = p ^ ((r >> 1) & 3);
      cp16(A + (long)(m0 + r) * lda + k0 + kc * 8, &As[lin2 * 8]);
    }
#pragma unroll
    for (int it = 0; it < 2; ++it) {
      int lin2 = it * 256 + tid;
      int r = lin2 >> 2;
      int p = lin2 & 3;
      int kc = p ^ ((r >> 1) & 3);
      cp16(B + (long)(n0 + r) * ldb + k0 + kc * 8, &Bs[lin2 * 8]);
    }
    __syncthreads();

    short8v af[4], bfr[4];
#pragma unroll
    for (int i = 0; i < 4; ++i)
      af[i] = *(const short8v*)(As + (wm + i * 16 + l15) * 32 + cp * 8);
#pragma unroll
    for (int j = 0; j < 4; ++j)
      bfr[j] = *(const short8v*)(Bs + (wn + j * 16 + l15) * 32 + cp * 8);
#pragma unroll
    for (int i = 0; i < 4; ++i)
#pragma unroll
      for (int j = 0; j < 4; ++j)
        acc[i][j] = __builtin_amdgcn_mfma_f32_16x16x32_bf16(af[i], bfr[j],
                                                            acc[i][j], 0, 0, 0);
    __syncthreads();
  }

  // ---- epilogues (C/D layout: col=lane&15 group, row=quad*4+reg) ----
  if constexpr (MODE == 3) {
#pragma unroll
    for (int j = 0; j < 4; ++j) {
      int col = n0 + wn + j * 16 + l15;
      float s = 0.f;
#pragma unroll
      for (int i = 0; i < 4; ++i)
#pragma unroll
        for (int reg = 0; reg < 4; ++reg) {
          float v = acc[i][j][reg];
          s += v > 0.f ? v : (__expf(v) - 1.f);
        }
      s += __shfl_xor(s, 16);
      s += __shfl_xor(s, 32);
      if (quad == 0) atomicAdd(Cf + (long)z * HID + col, s * (1.0f / NN));
    }
  } else {  // MODE 0: a-dot + transposed Ct via LDS [col][row] (stride 136)
    float a1v[4], a2v[4];
#pragma unroll
    for (int j = 0; j < 4; ++j) {
      int colh = n0 + wn + j * 16 + l15;  // single-head output (N=768)
      a1v[j] = a_vec[colh];
      a2v[j] = a_vec[HID + colh];
    }
#pragma unroll
    for (int i = 0; i < 4; ++i) {
      int rb = m0 + wm + i * 16 + quad * 4;
#pragma unroll
      for (int reg = 0; reg < 4; ++reg) {
        float s1 = 0.f, s2 = 0.f;
#pragma unroll
        for (int j = 0; j < 4; ++j) {
          s1 = fmaf(acc[i][j][reg], a1v[j], s1);
          s2 = fmaf(acc[i][j][reg], a2v[j], s2);
        }
#pragma unroll
        for (int off = 1; off < 16; off <<= 1) {
          s1 += __shfl_xor(s1, off);
          s2 += __shfl_xor(s2, off);
        }
        if (l15 == 0) {
          atomicAdd(Wh1g + rb + reg, s1);
          atomicAdd(Wh2g + rb + reg, s2);
        }
      }
    }
    const int bb = m0 >> 11;
    const int ml0 = m0 & 2047;
#pragma unroll
    for (int p = 0; p < 2; ++p) {
      if (wn == p * 64) {
#pragma unroll
        for (int j = 0; j < 4; ++j) {
          int col_l = j * 16 + l15;
#pragma unroll
          for (int i = 0; i < 4; ++i) {
            int row_l = wm + i * 16 + quad * 4;
            short4v pk;
#pragma unroll
            for (int reg = 0; reg < 4; ++reg) pk[reg] = f2bf(acc[i][j][reg]);
            *(short4v*)(smem + col_l * 136 + row_l) = pk;
          }
        }
      }
      __syncthreads();
#pragma unroll
      for (int it = 0; it < 4; ++it) {
        int idx = it * 256 + tid;
        int col_l = idx >> 4;
        int ch = idx & 15;
        short8v ld = *(const short8v*)(smem + col_l * 136 + ch * 8);
        int colh = n0 + p * 64 + col_l;
        *(short8v*)(Ct + ((long)bb * HID + colh) * NN + ml0 + ch * 8) = ld;
      }
      __syncthreads();
    }
  }
}

// ---------------------------------------------------------------------------
// Layer-2 row softmax (materializing, bf16 att). grid 16384. Blocks [0,zn)
// also zero zA (final output accumulator; write-disjoint from reads).
// ---------------------------------------------------------------------------
__global__ __launch_bounds__(256) void attn_softmax_kernel(
    const float* __restrict__ Wh1, const float* __restrict__ Wh2,
    const unsigned long long* __restrict__ packed, short* __restrict__ att,
    float* __restrict__ zA, int zn) {
  int row = blockIdx.x;
  if (row < zn) zA[row * 256 + threadIdx.x] = 0.f;
  int b = row >> 11;
  const unsigned char* bits = (const unsigned char*)(packed + (long)row * 32);
  const float* wh2b = Wh2 + b * NN;
  const int t = threadIdx.x;
  const int lane = t & 63;
  const int wv = t >> 6;

  unsigned m8 = bits[t];
  float wh1 = Wh1[row];
  float4 wa = ((const float4*)(wh2b + t * 8))[0];
  float4 wb = ((const float4*)(wh2b + t * 8))[1];
  float v[8] = {wa.x, wa.y, wa.z, wa.w, wb.x, wb.y, wb.z, wb.w};

  float lmax = -INFINITY;
#pragma unroll
  for (int k = 0; k < 8; ++k) {
    float s = wh1 + v[k];
    s = s > 0.f ? s : ALPHA * s;
    s = ((m8 >> k) & 1u) ? s : NEGV;
    v[k] = s;
    lmax = fmaxf(lmax, s);
  }

  __shared__ float redm[4], reds[4];
#pragma unroll
  for (int off = 32; off > 0; off >>= 1) lmax = fmaxf(lmax, __shfl_xor(lmax, off));
  if (lane == 0) redm[wv] = lmax;
  __syncthreads();
  float m = fmaxf(fmaxf(redm[0], redm[1]), fmaxf(redm[2], redm[3]));

  float lsum = 0.f;
#pragma unroll
  for (int k = 0; k < 8; ++k) {
    float p = __expf(v[k] - m);
    v[k] = p;
    lsum += p;
  }
#pragma unroll
  for (int off = 32; off > 0; off >>= 1) lsum += __shfl_xor(lsum, off);
  if (lane == 0) reds[wv] = lsum;
  __syncthreads();
  float inv = 1.f / (reds[0] + reds[1] + reds[2] + reds[3]);

  short8v o;
#pragma unroll
  for (int k = 0; k < 8; ++k) o[k] = f2bf(v[k] * inv);
  *(short8v*)(att + (long)row * NN + t * 8) = o;
}

// ---------------------------------------------------------------------------
extern "C" void kernel_launch(void* const* d_in, const int* in_sizes, int n_in,
                              void* d_out, int out_size, void* d_ws,
                              size_t ws_size, hipStream_t stream) {
  const int* node_feats = (const int*)d_in[0];
  const int* adjs = (const int*)d_in[1];
  const float* embed_table = (const float*)d_in[2];
  const float* W_heads = (const float*)d_in[3];
  const float* a_heads = (const float*)d_in[4];
  const float* W_out = (const float*)d_in[5];
  const float* a_out = (const float*)d_in[6];
  float* out = (float*)d_out;

  // workspace layout (~210 MB)
  char* p = (char*)d_ws;
  short* Wt_o = (short*)p;  p += (size_t)HID * (NHEADS * HID) * 2;       // 4.7 MB
  short* Wh_t = (short*)p;  p += (size_t)BB * HID * NN * 2;              // 25 MB
  short* att2 = (short*)p;  p += (size_t)BB * NN * NN * 2;               // 67 MB
  short* hcat = (short*)p;  p += (size_t)MTOT * NHEADS * HID * 2;        // 100 MB
  unsigned long long* padj = (unsigned long long*)p;
  p += (size_t)BB * NN * NN / 8;                                         // 4.2 MB
  float* P16 = (float*)p;   p += (size_t)NHEADS * 16384 * 16 * 4;        // 4 MB
  // contiguous zero region: Wh1 (16384) + Wh2 (16384) + TW (46080)
  float* Wh1 = (float*)p;   p += (size_t)16384 * 4;
  float* Wh2 = (float*)p;   p += (size_t)16384 * 4;
  float* TW = (float*)p;    p += (size_t)VOCAB * NHEADS * HID * 4;
  float* TW1 = (float*)p;   p += (size_t)NHEADS * VOCAB * 4;
  float* TW2 = (float*)p;   p += (size_t)NHEADS * VOCAB * 4;
  unsigned long long* nfm = (unsigned long long*)p;
  p += (size_t)BB * VOCAB * 32 * 8;                                      // 30 KB
  if ((size_t)(p - (char*)d_ws) > ws_size) return;

  // 0) mega-setup: adj pack + zeros + vocab masks + W_out transpose
  setup_kernel<<<PACK_B + ZERO_B + NFM_B + TRAN_B, 256, 0, stream>>>(
      adjs, padj, Wh1, node_feats, nfm, W_out, Wt_o);

  // 1) layer 1 via rank-15 structure: TW, a-dots, popcount-P16, expand
  tw_kernel<<<dim3(12, 16), 256, 0, stream>>>(embed_table, W_heads, TW);
  tw12_kernel<<<NHEADS * VOCAB, 256, 0, stream>>>(TW, a_heads, TW1, TW2);
  p16_kernel<<<16384 / 4, 256, 0, stream>>>(
      node_feats, (const unsigned*)padj, (const unsigned*)nfm, TW1, TW2, P16);
  hcat_expand<<<dim3(24, 128), 256, 0, stream>>>(TW, P16, hcat);

  // 2) output GAT layer (full-rank): proj2 -> Wh_t + Wh1/Wh2 atomics
  mfma_gemm<0><<<dim3(HID / 128, MTOT / 128, 1), 256, 0, stream>>>(
      hcat, Wt_o, NHEADS * HID, NHEADS * HID, NHEADS * HID, 0, 0,
      nullptr, Wh_t, a_out, Wh1, Wh2);
  attn_softmax_kernel<<<MTOT, 256, 0, stream>>>(Wh1, Wh2, padj, att2, out, 24);
  mfma_gemm<3><<<dim3(HID / 128, NN / 128, BB), 256, 0, stream>>>(
      att2, Wh_t, NN, NN, NN, (long)NN * NN, (long)HID * NN,
      out, nullptr, nullptr, nullptr, nullptr);
}